// Round 9
// baseline (269.595 us; speedup 1.0000x reference)
//
#include <hip/hip_runtime.h>

// HGCN on MI355X. logmap0(expmap0(v)) == v here, so the model reduces to:
//   t1 = sigmoid(segmean(feat@W1+b1)); t2 = sigmoid(segmean(t1@W2+b2))
//   out = relu(t2@W3+b3)@W4 + b4     (and segmean commutes with the linear map)
// R1: fp32 atomicAdd scatter = atomic wall -> counting-sort CSR + gather.
// R2: single-block scan = latency wall -> hierarchical scan.
// R3: 4B random scatter write-allocates 64B lines -> coarse buckets.
// R4: global atomics on few counters = contention wall -> LDS-staged radix.
// R5: agg gather byte-bound -> bf16 rows, pack CSR.
// R6: fp32 MLP LDS-bound -> MFMA epilogue.
// R8: aggregate before GEMM (linearity); bf16 MFMA everywhere.
// R9: ep3's 2.85M LDS conflicts were per-block f2bf b16 staging writes ->
//     prep_k builds padded bf16 weight images ONCE; blocks stage via uint4
//     copies. Gather fused into the MFMA kernels (aggF roundtrip deleted).

constexpr int CSHIFT = 9;               // 512 nodes per coarse bucket
constexpr int CNODES = 1 << CSHIFT;
constexpr int EPB    = 4096;            // edges per partition block
constexpr int EPT    = EPB / 256;
constexpr int CAP    = 16384;           // arena capacity per bucket (mean 8163)

// bf16 weight-image layout (shorts), strides padded for 16B-aligned short8
constexpr int W1_OFF = 0;                     // 64 rows x 72
constexpr int W2_OFF = 64 * 72;               // 64 rows x 72
constexpr int W3_OFF = W2_OFF + 64 * 72;      // 128 rows x 72
constexpr int W4_OFF = W3_OFF + 128 * 72;     // 48 rows x 136
constexpr int WIMG_TOT = W4_OFF + 48 * 136;   // 24960 shorts
constexpr int W234_SH = WIMG_TOT - W2_OFF;    // 20352 shorts, contiguous

typedef __attribute__((ext_vector_type(8))) short short8;   // 8 bf16
typedef __attribute__((ext_vector_type(4))) float floatx4;  // MFMA acc

__device__ __forceinline__ float sigmoidf(float x) {
    return 1.0f / (1.0f + __expf(-x));
}
__device__ __forceinline__ unsigned short f2bf(float f) {   // RNE f32->bf16
    unsigned int u = __float_as_uint(f);
    u = (u + 0x7FFFu + ((u >> 16) & 1u)) >> 16;
    return (unsigned short)u;
}

// ---------------- one-time prep ----------------
__global__ __launch_bounds__(256) void cast_k(const float* __restrict__ in,
                                              unsigned short* __restrict__ out,
                                              int n8) {
    int i = blockIdx.x * 256 + threadIdx.x;
    if (i >= n8) return;
    const float4* p = (const float4*)in + (size_t)i * 2;
    float4 a = p[0], b = p[1];
    uint4 o;
    o.x = (unsigned)f2bf(a.x) | ((unsigned)f2bf(a.y) << 16);
    o.y = (unsigned)f2bf(a.z) | ((unsigned)f2bf(a.w) << 16);
    o.z = (unsigned)f2bf(b.x) | ((unsigned)f2bf(b.y) << 16);
    o.w = (unsigned)f2bf(b.z) | ((unsigned)f2bf(b.w) << 16);
    ((uint4*)out)[i] = o;
}

// Build transposed bf16 weight images in the exact (padded) LDS layout.
__global__ __launch_bounds__(256) void prep_k(const float* __restrict__ W1,
                                              const float* __restrict__ W2,
                                              const float* __restrict__ W3,
                                              const float* __restrict__ W4,
                                              unsigned short* __restrict__ img) {
    int i = blockIdx.x * 256 + threadIdx.x;
    if (i >= WIMG_TOT) return;
    float v = 0.f;
    if (i < W2_OFF) {
        int j = i, n = j / 72, k = j % 72;
        if (k < 64) v = W1[k * 64 + n];
    } else if (i < W3_OFF) {
        int j = i - W2_OFF, n = j / 72, k = j % 72;
        if (k < 64) v = W2[k * 64 + n];
    } else if (i < W4_OFF) {
        int j = i - W3_OFF, n = j / 72, k = j % 72;
        if (k < 64) v = W3[k * 128 + n];
    } else {
        int j = i - W4_OFF, n = j / 136, k = j % 136;
        if (n < 40 && k < 128) v = W4[k * 40 + n];
    }
    img[i] = f2bf(v);
}

// ---------------- CSR build ----------------
__global__ __launch_bounds__(256) void part_a(const int* __restrict__ src,
                                              const int* __restrict__ dst,
                                              int* __restrict__ ccur,
                                              int* __restrict__ arena,
                                              int E, int NBUCK) {
    __shared__ int  hist[256];
    __shared__ int  exoff[256];
    __shared__ int  lcur[256];
    __shared__ int  gbase[256];
    __shared__ int  stage[EPB];
    __shared__ unsigned char stageB[EPB];

    const int tid = threadIdx.x;
    const int e0  = blockIdx.x * EPB;
    const int ec  = min(EPB, E - e0);

    int pk[EPT], bk[EPT];
    hist[tid] = 0;
    __syncthreads();
    #pragma unroll
    for (int j = 0; j < EPT; j++) {
        int idx = tid + j * 256;
        if (idx < ec) {
            int s = src[e0 + idx];
            int d = dst[e0 + idx];
            bk[j] = d >> CSHIFT;
            pk[j] = s | ((d & (CNODES - 1)) << 17);
            atomicAdd(&hist[bk[j]], 1);
        } else bk[j] = -1;
    }
    __syncthreads();
    const int h = hist[tid];
    exoff[tid] = h;
    __syncthreads();
    for (int dd = 1; dd < 256; dd <<= 1) {
        int v = 0;
        if (tid >= dd) v = exoff[tid - dd];
        __syncthreads();
        if (tid >= dd) exoff[tid] += v;
        __syncthreads();
    }
    const int ex = exoff[tid] - h;
    int gb = 0;
    if (tid < NBUCK && h > 0) gb = atomicAdd(ccur + tid, h);
    __syncthreads();
    exoff[tid] = ex;
    lcur[tid]  = ex;
    gbase[tid] = gb;
    __syncthreads();
    #pragma unroll
    for (int j = 0; j < EPT; j++) {
        if (bk[j] >= 0) {
            int l = atomicAdd(&lcur[bk[j]], 1);
            stage[l]  = pk[j];
            stageB[l] = (unsigned char)bk[j];
        }
    }
    __syncthreads();
    for (int i = tid; i < ec; i += 256) {
        int b = stageB[i];
        arena[(size_t)b * CAP + gbase[b] + (i - exoff[b])] = stage[i];
    }
}

__global__ __launch_bounds__(256) void scanc_k(const int* __restrict__ ccur,
                                               int* __restrict__ coff,
                                               int* __restrict__ offN,
                                               int NBUCK, int E) {
    __shared__ int sh[256];
    const int tid = threadIdx.x;
    sh[tid] = (tid < NBUCK) ? ccur[tid] : 0;
    __syncthreads();
    for (int d = 1; d < 256; d <<= 1) {
        int v = 0;
        if (tid >= d) v = sh[tid - d];
        __syncthreads();
        if (tid >= d) sh[tid] += v;
        __syncthreads();
    }
    if (tid < NBUCK) coff[tid] = (tid > 0) ? sh[tid - 1] : 0;
    if (tid == 0) { coff[NBUCK] = E; *offN = E; }
}

__global__ __launch_bounds__(256) void csr_fine(const int* __restrict__ arena,
                                                const int* __restrict__ coff,
                                                int* __restrict__ off,
                                                int* __restrict__ ssrc, int N) {
    __shared__ int cnt[CNODES];
    __shared__ int cur[CNODES];
    __shared__ int part[256];
    const int b = blockIdx.x;
    const int node0 = b << CSHIFT;
    const int cbeg = coff[b];
    const int ec   = coff[b + 1] - cbeg;
    const int* pe  = arena + (size_t)b * CAP;
    const int tid = threadIdx.x;

    cnt[tid] = 0;
    cnt[tid + 256] = 0;
    __syncthreads();
    for (int i = tid; i < ec; i += 256)
        atomicAdd(&cnt[(pe[i] >> 17) & (CNODES - 1)], 1);
    __syncthreads();
    const int c0 = cnt[2 * tid], c1 = cnt[2 * tid + 1];
    part[tid] = c0 + c1;
    __syncthreads();
    for (int d = 1; d < 256; d <<= 1) {
        int v = 0;
        if (tid >= d) v = part[tid - d];
        __syncthreads();
        if (tid >= d) part[tid] += v;
        __syncthreads();
    }
    const int ex = (tid > 0) ? part[tid - 1] : 0;
    cur[2 * tid]     = ex;
    cur[2 * tid + 1] = ex + c0;
    if (node0 + 2 * tid     < N) off[node0 + 2 * tid]     = cbeg + ex;
    if (node0 + 2 * tid + 1 < N) off[node0 + 2 * tid + 1] = cbeg + ex + c0;
    __syncthreads();
    for (int i = tid; i < ec; i += 256) {
        int p = pe[i];
        int pos = cbeg + atomicAdd(&cur[(p >> 17) & (CNODES - 1)], 1);
        ssrc[pos] = p & 0x1FFFF;
    }
}

// ---------------- gather helper: mean of h[src] into LDS tile ----------------
#define ACC8(v)                                    \
    acc[0] += __uint_as_float((v).x << 16);        \
    acc[1] += __uint_as_float((v).x & 0xFFFF0000u);\
    acc[2] += __uint_as_float((v).y << 16);        \
    acc[3] += __uint_as_float((v).y & 0xFFFF0000u);\
    acc[4] += __uint_as_float((v).z << 16);        \
    acc[5] += __uint_as_float((v).z & 0xFFFF0000u);\
    acc[6] += __uint_as_float((v).w << 16);        \
    acc[7] += __uint_as_float((v).w & 0xFFFF0000u);

// 256 threads = 32 nodes x 8 lanes; 2 passes cover a 64-row tile.
// Writes bf16 rows into Agg (stride 72 shorts); zero-fills tail rows.
__device__ __forceinline__ void gather_tile(
    const unsigned short* __restrict__ h, const int* __restrict__ off,
    const int* __restrict__ ssrc, unsigned short* Agg, int rowB, int N, int tid)
{
    #pragma unroll
    for (int pass = 0; pass < 2; pass++) {
        int rl = pass * 32 + (tid >> 3);
        int g  = rowB + rl;
        int q  = (tid & 7) * 8;
        uint4 p = make_uint4(0u, 0u, 0u, 0u);
        if (g < N) {
            int beg = off[g], end = off[g + 1];
            float acc[8] = {0.f, 0.f, 0.f, 0.f, 0.f, 0.f, 0.f, 0.f};
            int i = beg;
            for (; i + 4 <= end; i += 4) {
                int s0 = ssrc[i], s1 = ssrc[i+1], s2 = ssrc[i+2], s3 = ssrc[i+3];
                uint4 v0 = *(const uint4*)(h + (size_t)s0 * 64 + q);
                uint4 v1 = *(const uint4*)(h + (size_t)s1 * 64 + q);
                uint4 v2 = *(const uint4*)(h + (size_t)s2 * 64 + q);
                uint4 v3 = *(const uint4*)(h + (size_t)s3 * 64 + q);
                ACC8(v0); ACC8(v1); ACC8(v2); ACC8(v3);
            }
            for (; i < end; i++) {
                int s = ssrc[i];
                uint4 v = *(const uint4*)(h + (size_t)s * 64 + q);
                ACC8(v);
            }
            float inv = 1.0f / (float)max(end - beg, 1);
            p.x = (unsigned)f2bf(acc[0]*inv) | ((unsigned)f2bf(acc[1]*inv) << 16);
            p.y = (unsigned)f2bf(acc[2]*inv) | ((unsigned)f2bf(acc[3]*inv) << 16);
            p.z = (unsigned)f2bf(acc[4]*inv) | ((unsigned)f2bf(acc[5]*inv) << 16);
            p.w = (unsigned)f2bf(acc[6]*inv) | ((unsigned)f2bf(acc[7]*inv) << 16);
        }
        *(uint4*)(Agg + rl * 72 + q) = p;
    }
}

// ---------------- fused gather + GEMM1 + sigmoid -> t1 ----------------
__global__ __launch_bounds__(256) void aggemm1_k(
    const unsigned short* __restrict__ featbf, const int* __restrict__ off,
    const int* __restrict__ ssrc, const unsigned short* __restrict__ img,
    const float* __restrict__ b1, unsigned short* __restrict__ t1, int N)
{
    __shared__ alignas(16) unsigned short Wt[64 * 72];
    __shared__ alignas(16) unsigned short Agg[64 * 72];
    __shared__ float bs[64];
    __shared__ unsigned char dz[64];

    const int tid = threadIdx.x;
    const int rowB = blockIdx.x * 64;
    {   // conflict-free b128 staging from pre-built image
        const uint4* s = (const uint4*)(img + W1_OFF);
        uint4* d = (uint4*)Wt;
        #pragma unroll
        for (int i = 0; i < 576 / 256 + 1; i++) {
            int idx = tid + i * 256;
            if (idx < 576) d[idx] = s[idx];
        }
    }
    if (tid < 64) {
        bs[tid] = b1[tid];
        int row = rowB + tid;
        dz[tid] = (row < N) ? (off[row + 1] == off[row]) : 0;
    }
    gather_tile(featbf, off, ssrc, Agg, rowB, N, tid);
    __syncthreads();

    const int w = tid >> 6, lane = tid & 63;
    const int m = lane & 15, quad = lane >> 4;

    floatx4 acc[4];
    #pragma unroll
    for (int c = 0; c < 4; c++) acc[c] = (floatx4){0.f, 0.f, 0.f, 0.f};
    #pragma unroll
    for (int kk = 0; kk < 64; kk += 32) {
        short8 a = *(const short8*)(Agg + (w * 16 + m) * 72 + kk + quad * 8);
        #pragma unroll
        for (int c = 0; c < 4; c++) {
            short8 b = *(const short8*)(Wt + (c * 16 + m) * 72 + kk + quad * 8);
            acc[c] = __builtin_amdgcn_mfma_f32_16x16x32_bf16(a, b, acc[c], 0, 0, 0);
        }
    }
    #pragma unroll
    for (int c = 0; c < 4; c++) {
        int col = c * 16 + m;
        #pragma unroll
        for (int r = 0; r < 4; r++) {
            int rl = w * 16 + quad * 4 + r;
            int row = rowB + rl;
            if (row < N) {
                float v = dz[rl] ? 0.5f : sigmoidf(acc[c][r] + bs[col]);
                t1[(size_t)row * 64 + col] = f2bf(v);
            }
        }
    }
}

// ---------------- fused gather + GEMM2/3/4 -> out ----------------
__global__ __launch_bounds__(256) void ep4_k(
    const unsigned short* __restrict__ t1, const int* __restrict__ off,
    const int* __restrict__ ssrc, const unsigned short* __restrict__ img,
    const float* __restrict__ b2, const float* __restrict__ b3,
    const float* __restrict__ b4, float* __restrict__ out, int N)
{
    __shared__ alignas(16) unsigned short W234[W234_SH];   // 39.8 KB
    __shared__ alignas(16) unsigned short Agg[64 * 72];    // 9.0 KB
    __shared__ alignas(16) unsigned short T2[64 * 72];     // 9.0 KB
    __shared__ alignas(16) unsigned short H3[64 * 136];    // 17.0 KB
    __shared__ float b2s[64], b3s[128], b4s[48];
    __shared__ unsigned char dz[64];

    const unsigned short* W2T = W234;                 // 64 x 72
    const unsigned short* W3T = W234 + 64 * 72;       // 128 x 72
    const unsigned short* W4T = W234 + 64 * 72 + 128 * 72;  // 48 x 136

    const int tid = threadIdx.x;
    const int rowB = blockIdx.x * 64;
    {   // one contiguous conflict-free copy of all three weight images
        const uint4* s = (const uint4*)(img + W2_OFF);
        uint4* d = (uint4*)W234;
        for (int i = tid; i < W234_SH / 8; i += 256) d[i] = s[i];
    }
    if (tid < 64) {
        b2s[tid] = b2[tid];
        int row = rowB + tid;
        dz[tid] = (row < N) ? (off[row + 1] == off[row]) : 0;
    }
    if (tid < 128) b3s[tid] = b3[tid];
    if (tid < 48)  b4s[tid] = (tid < 40) ? b4[tid] : 0.f;
    gather_tile(t1, off, ssrc, Agg, rowB, N, tid);
    __syncthreads();

    const int w = tid >> 6, lane = tid & 63;
    const int m = lane & 15, quad = lane >> 4;

    // ---- phase 0: T2 = sigmoid(Agg @ W2 + b2) ----
    {
        floatx4 acc[4];
        #pragma unroll
        for (int c = 0; c < 4; c++) acc[c] = (floatx4){0.f, 0.f, 0.f, 0.f};
        #pragma unroll
        for (int kk = 0; kk < 64; kk += 32) {
            short8 a = *(const short8*)(Agg + (w * 16 + m) * 72 + kk + quad * 8);
            #pragma unroll
            for (int c = 0; c < 4; c++) {
                short8 b = *(const short8*)(W2T + (c * 16 + m) * 72 + kk + quad * 8);
                acc[c] = __builtin_amdgcn_mfma_f32_16x16x32_bf16(a, b, acc[c], 0, 0, 0);
            }
        }
        #pragma unroll
        for (int c = 0; c < 4; c++) {
            int col = c * 16 + m;
            #pragma unroll
            for (int r = 0; r < 4; r++) {
                int rl = w * 16 + quad * 4 + r;
                float v = dz[rl] ? 0.5f : sigmoidf(acc[c][r] + b2s[col]);
                T2[rl * 72 + col] = f2bf(v);
            }
        }
    }
    __syncthreads();

    // ---- phase 1: H3 = relu(T2 @ W3 + b3) ----
    {
        floatx4 acc[8];
        #pragma unroll
        for (int c = 0; c < 8; c++) acc[c] = (floatx4){0.f, 0.f, 0.f, 0.f};
        #pragma unroll
        for (int kk = 0; kk < 64; kk += 32) {
            short8 a = *(const short8*)(T2 + (w * 16 + m) * 72 + kk + quad * 8);
            #pragma unroll
            for (int c = 0; c < 8; c++) {
                short8 b = *(const short8*)(W3T + (c * 16 + m) * 72 + kk + quad * 8);
                acc[c] = __builtin_amdgcn_mfma_f32_16x16x32_bf16(a, b, acc[c], 0, 0, 0);
            }
        }
        #pragma unroll
        for (int c = 0; c < 8; c++) {
            int col = c * 16 + m;
            #pragma unroll
            for (int r = 0; r < 4; r++) {
                int rl = w * 16 + quad * 4 + r;
                H3[rl * 136 + col] = f2bf(fmaxf(acc[c][r] + b3s[col], 0.f));
            }
        }
    }
    __syncthreads();

    // ---- phase 2: out = H3 @ W4 + b4 ----
    {
        floatx4 acc[3];
        #pragma unroll
        for (int c = 0; c < 3; c++) acc[c] = (floatx4){0.f, 0.f, 0.f, 0.f};
        #pragma unroll
        for (int kk = 0; kk < 128; kk += 32) {
            short8 a = *(const short8*)(H3 + (w * 16 + m) * 136 + kk + quad * 8);
            #pragma unroll
            for (int c = 0; c < 3; c++) {
                short8 b = *(const short8*)(W4T + (c * 16 + m) * 136 + kk + quad * 8);
                acc[c] = __builtin_amdgcn_mfma_f32_16x16x32_bf16(a, b, acc[c], 0, 0, 0);
            }
        }
        #pragma unroll
        for (int c = 0; c < 3; c++) {
            int col = c * 16 + m;
            if (col < 40) {
                #pragma unroll
                for (int r = 0; r < 4; r++) {
                    int row = rowB + w * 16 + quad * 4 + r;
                    if (row < N) out[(size_t)row * 40 + col] = acc[c][r] + b4s[col];
                }
            }
        }
    }
}

extern "C" void kernel_launch(void* const* d_in, const int* in_sizes, int n_in,
                              void* d_out, int out_size, void* d_ws, size_t ws_size,
                              hipStream_t stream)
{
    const float* feat = (const float*)d_in[0];
    const int*   eidx = (const int*)d_in[1];
    const float* W1 = (const float*)d_in[2];
    const float* b1 = (const float*)d_in[3];
    const float* W2 = (const float*)d_in[4];
    const float* b2 = (const float*)d_in[5];
    const float* W3 = (const float*)d_in[6];
    const float* b3 = (const float*)d_in[7];
    const float* W4 = (const float*)d_in[8];
    const float* b4 = (const float*)d_in[9];

    const int N = in_sizes[0] / 64;
    const int E = in_sizes[1] / 2;
    const int* src = eidx;
    const int* dst = eidx + E;

    const int NBUCK = (N + CNODES - 1) / CNODES;   // 196

    unsigned short* featbf = (unsigned short*)d_ws;            // N*64 bf16
    unsigned short* t1     = featbf + (size_t)N * 64;          // N*64 bf16
    unsigned short* img    = t1     + (size_t)N * 64;          // WIMG_TOT
    int*   off   = (int*)(img + ((WIMG_TOT + 7) & ~7));        // N+1
    int*   ccur  = off + (N + 1);                              // NBUCK
    int*   coff  = ccur + NBUCK;                               // NBUCK+1
    int*   ssrc  = coff + (NBUCK + 1);                         // E
    int*   arena = ssrc + E;                                   // NBUCK*CAP
    float* out   = (float*)d_out;

    hipMemsetAsync(ccur, 0, (size_t)NBUCK * sizeof(int), stream);

    const dim3 blk(256);
    const int gP  = (E + EPB - 1) / EPB;
    const int g64 = (N + 63) / 64;
    const int gC  = (N * 64 / 8 + 255) / 256;
    const int gW  = (WIMG_TOT + 255) / 256;

    // one-time prep + CSR build (shared by both aggregation rounds)
    cast_k<<<gC, blk, 0, stream>>>(feat, featbf, N * 64 / 8);
    prep_k<<<gW, blk, 0, stream>>>(W1, W2, W3, W4, img);
    part_a<<<gP, blk, 0, stream>>>(src, dst, ccur, arena, E, NBUCK);
    scanc_k<<<1, blk, 0, stream>>>(ccur, coff, off + N, NBUCK, E);
    csr_fine<<<NBUCK, blk, 0, stream>>>(arena, coff, off, ssrc, N);

    // t1 = sigmoid(mean(featbf[src]) @ W1 + b1)     [gather fused]
    aggemm1_k<<<g64, blk, 0, stream>>>(featbf, off, ssrc, img, b1, t1, N);
    // out = relu(sigmoid(mean(t1[src])@W2+b2)@W3+b3)@W4 + b4   [gather fused]
    ep4_k<<<g64, blk, 0, stream>>>(t1, off, ssrc, img, b2, b3, b4, out, N);
}

// Round 10
// 246.105 us; speedup vs baseline: 1.0954x; 1.0954x over previous
//
#include <hip/hip_runtime.h>

// HGCN on MI355X. logmap0(expmap0(v)) == v here, so the model reduces to:
//   t1 = sigmoid(segmean(feat@W1+b1)); t2 = sigmoid(segmean(t1@W2+b2))
//   out = relu(t2@W3+b3)@W4 + b4     (segmean commutes with the linear map)
// R1: fp32 atomicAdd scatter = atomic wall -> counting-sort CSR + gather.
// R2: single-block scan = latency wall -> hierarchical scan.
// R3: 4B random scatter write-allocates 64B lines -> coarse buckets.
// R4: global atomics on few counters = contention wall -> LDS-staged radix.
// R5: agg gather byte-bound -> bf16 rows, pack CSR.
// R6: fp32 MLP LDS-bound -> MFMA epilogue.
// R8: aggregate before GEMM (linearity); bf16 MFMA everywhere.
// R9 half-win: pre-built bf16 weight images kill staging conflicts. But
//   fusing the latency-bound gather into the 2-block/CU MFMA kernel dropped
//   gather occupancy 52%->17% and LOST time.
// R10: unfuse. High-occupancy standalone agg_k + image-staged MFMA kernels.

constexpr int CSHIFT = 9;               // 512 nodes per coarse bucket
constexpr int CNODES = 1 << CSHIFT;
constexpr int EPB    = 4096;            // edges per partition block
constexpr int EPT    = EPB / 256;
constexpr int CAP    = 16384;           // arena capacity per bucket (mean 8163)

// bf16 weight-image layout (shorts), strides padded for 16B-aligned short8
constexpr int W1_OFF = 0;                     // 64 rows x 72
constexpr int W2_OFF = 64 * 72;               // 64 rows x 72
constexpr int W3_OFF = W2_OFF + 64 * 72;      // 128 rows x 72
constexpr int W4_OFF = W3_OFF + 128 * 72;     // 48 rows x 136
constexpr int WIMG_TOT = W4_OFF + 48 * 136;   // 24960 shorts
constexpr int W234_SH = WIMG_TOT - W2_OFF;    // 20352 shorts, contiguous

typedef __attribute__((ext_vector_type(8))) short short8;   // 8 bf16
typedef __attribute__((ext_vector_type(4))) float floatx4;  // MFMA acc

__device__ __forceinline__ float sigmoidf(float x) {
    return 1.0f / (1.0f + __expf(-x));
}
__device__ __forceinline__ unsigned short f2bf(float f) {   // RNE f32->bf16
    unsigned int u = __float_as_uint(f);
    u = (u + 0x7FFFu + ((u >> 16) & 1u)) >> 16;
    return (unsigned short)u;
}

// ---------------- one-time prep ----------------
__global__ __launch_bounds__(256) void cast_k(const float* __restrict__ in,
                                              unsigned short* __restrict__ out,
                                              int n8) {
    int i = blockIdx.x * 256 + threadIdx.x;
    if (i >= n8) return;
    const float4* p = (const float4*)in + (size_t)i * 2;
    float4 a = p[0], b = p[1];
    uint4 o;
    o.x = (unsigned)f2bf(a.x) | ((unsigned)f2bf(a.y) << 16);
    o.y = (unsigned)f2bf(a.z) | ((unsigned)f2bf(a.w) << 16);
    o.z = (unsigned)f2bf(b.x) | ((unsigned)f2bf(b.y) << 16);
    o.w = (unsigned)f2bf(b.z) | ((unsigned)f2bf(b.w) << 16);
    ((uint4*)out)[i] = o;
}

// Build transposed bf16 weight images in the exact (padded) LDS layout.
__global__ __launch_bounds__(256) void prep_k(const float* __restrict__ W1,
                                              const float* __restrict__ W2,
                                              const float* __restrict__ W3,
                                              const float* __restrict__ W4,
                                              unsigned short* __restrict__ img) {
    int i = blockIdx.x * 256 + threadIdx.x;
    if (i >= WIMG_TOT) return;
    float v = 0.f;
    if (i < W2_OFF) {
        int j = i, n = j / 72, k = j % 72;
        if (k < 64) v = W1[k * 64 + n];
    } else if (i < W3_OFF) {
        int j = i - W2_OFF, n = j / 72, k = j % 72;
        if (k < 64) v = W2[k * 64 + n];
    } else if (i < W4_OFF) {
        int j = i - W3_OFF, n = j / 72, k = j % 72;
        if (k < 64) v = W3[k * 128 + n];
    } else {
        int j = i - W4_OFF, n = j / 136, k = j % 136;
        if (n < 40 && k < 128) v = W4[k * 40 + n];
    }
    img[i] = f2bf(v);
}

// ---------------- CSR build ----------------
__global__ __launch_bounds__(256) void part_a(const int* __restrict__ src,
                                              const int* __restrict__ dst,
                                              int* __restrict__ ccur,
                                              int* __restrict__ arena,
                                              int E, int NBUCK) {
    __shared__ int  hist[256];
    __shared__ int  exoff[256];
    __shared__ int  lcur[256];
    __shared__ int  gbase[256];
    __shared__ int  stage[EPB];
    __shared__ unsigned char stageB[EPB];

    const int tid = threadIdx.x;
    const int e0  = blockIdx.x * EPB;
    const int ec  = min(EPB, E - e0);

    int pk[EPT], bk[EPT];
    hist[tid] = 0;
    __syncthreads();
    #pragma unroll
    for (int j = 0; j < EPT; j++) {
        int idx = tid + j * 256;
        if (idx < ec) {
            int s = src[e0 + idx];
            int d = dst[e0 + idx];
            bk[j] = d >> CSHIFT;
            pk[j] = s | ((d & (CNODES - 1)) << 17);
            atomicAdd(&hist[bk[j]], 1);
        } else bk[j] = -1;
    }
    __syncthreads();
    const int h = hist[tid];
    exoff[tid] = h;
    __syncthreads();
    for (int dd = 1; dd < 256; dd <<= 1) {
        int v = 0;
        if (tid >= dd) v = exoff[tid - dd];
        __syncthreads();
        if (tid >= dd) exoff[tid] += v;
        __syncthreads();
    }
    const int ex = exoff[tid] - h;
    int gb = 0;
    if (tid < NBUCK && h > 0) gb = atomicAdd(ccur + tid, h);
    __syncthreads();
    exoff[tid] = ex;
    lcur[tid]  = ex;
    gbase[tid] = gb;
    __syncthreads();
    #pragma unroll
    for (int j = 0; j < EPT; j++) {
        if (bk[j] >= 0) {
            int l = atomicAdd(&lcur[bk[j]], 1);
            stage[l]  = pk[j];
            stageB[l] = (unsigned char)bk[j];
        }
    }
    __syncthreads();
    for (int i = tid; i < ec; i += 256) {
        int b = stageB[i];
        arena[(size_t)b * CAP + gbase[b] + (i - exoff[b])] = stage[i];
    }
}

__global__ __launch_bounds__(256) void scanc_k(const int* __restrict__ ccur,
                                               int* __restrict__ coff,
                                               int* __restrict__ offN,
                                               int NBUCK, int E) {
    __shared__ int sh[256];
    const int tid = threadIdx.x;
    sh[tid] = (tid < NBUCK) ? ccur[tid] : 0;
    __syncthreads();
    for (int d = 1; d < 256; d <<= 1) {
        int v = 0;
        if (tid >= d) v = sh[tid - d];
        __syncthreads();
        if (tid >= d) sh[tid] += v;
        __syncthreads();
    }
    if (tid < NBUCK) coff[tid] = (tid > 0) ? sh[tid - 1] : 0;
    if (tid == 0) { coff[NBUCK] = E; *offN = E; }
}

__global__ __launch_bounds__(256) void csr_fine(const int* __restrict__ arena,
                                                const int* __restrict__ coff,
                                                int* __restrict__ off,
                                                int* __restrict__ ssrc, int N) {
    __shared__ int cnt[CNODES];
    __shared__ int cur[CNODES];
    __shared__ int part[256];
    const int b = blockIdx.x;
    const int node0 = b << CSHIFT;
    const int cbeg = coff[b];
    const int ec   = coff[b + 1] - cbeg;
    const int* pe  = arena + (size_t)b * CAP;
    const int tid = threadIdx.x;

    cnt[tid] = 0;
    cnt[tid + 256] = 0;
    __syncthreads();
    for (int i = tid; i < ec; i += 256)
        atomicAdd(&cnt[(pe[i] >> 17) & (CNODES - 1)], 1);
    __syncthreads();
    const int c0 = cnt[2 * tid], c1 = cnt[2 * tid + 1];
    part[tid] = c0 + c1;
    __syncthreads();
    for (int d = 1; d < 256; d <<= 1) {
        int v = 0;
        if (tid >= d) v = part[tid - d];
        __syncthreads();
        if (tid >= d) part[tid] += v;
        __syncthreads();
    }
    const int ex = (tid > 0) ? part[tid - 1] : 0;
    cur[2 * tid]     = ex;
    cur[2 * tid + 1] = ex + c0;
    if (node0 + 2 * tid     < N) off[node0 + 2 * tid]     = cbeg + ex;
    if (node0 + 2 * tid + 1 < N) off[node0 + 2 * tid + 1] = cbeg + ex + c0;
    __syncthreads();
    for (int i = tid; i < ec; i += 256) {
        int p = pe[i];
        int pos = cbeg + atomicAdd(&cur[(p >> 17) & (CNODES - 1)], 1);
        ssrc[pos] = p & 0x1FFFF;
    }
}

// ---------------- aggregation: pure mean gather, bf16->bf16 ----------------
// Standalone, high-occupancy (latency-bound random gather needs waves).
#define ACC8(v)                                    \
    acc[0] += __uint_as_float((v).x << 16);        \
    acc[1] += __uint_as_float((v).x & 0xFFFF0000u);\
    acc[2] += __uint_as_float((v).y << 16);        \
    acc[3] += __uint_as_float((v).y & 0xFFFF0000u);\
    acc[4] += __uint_as_float((v).z << 16);        \
    acc[5] += __uint_as_float((v).z & 0xFFFF0000u);\
    acc[6] += __uint_as_float((v).w << 16);        \
    acc[7] += __uint_as_float((v).w & 0xFFFF0000u);

__global__ __launch_bounds__(256) void agg_k(const unsigned short* __restrict__ h,
                                             const int* __restrict__ off,
                                             const int* __restrict__ ssrc,
                                             unsigned short* __restrict__ outb,
                                             int N) {
    int t = blockIdx.x * 256 + threadIdx.x;
    int g = t >> 3;
    if (g >= N) return;
    int q = (t & 7) * 8;
    int beg = off[g], end = off[g + 1];
    float acc[8] = {0.f, 0.f, 0.f, 0.f, 0.f, 0.f, 0.f, 0.f};
    int i = beg;
    for (; i + 4 <= end; i += 4) {
        int s0 = ssrc[i], s1 = ssrc[i + 1], s2 = ssrc[i + 2], s3 = ssrc[i + 3];
        uint4 v0 = *(const uint4*)(h + (size_t)s0 * 64 + q);
        uint4 v1 = *(const uint4*)(h + (size_t)s1 * 64 + q);
        uint4 v2 = *(const uint4*)(h + (size_t)s2 * 64 + q);
        uint4 v3 = *(const uint4*)(h + (size_t)s3 * 64 + q);
        ACC8(v0); ACC8(v1); ACC8(v2); ACC8(v3);
    }
    for (; i < end; i++) {
        int s = ssrc[i];
        uint4 v = *(const uint4*)(h + (size_t)s * 64 + q);
        ACC8(v);
    }
    float inv = 1.0f / (float)max(end - beg, 1);
    uint4 p;
    p.x = (unsigned)f2bf(acc[0] * inv) | ((unsigned)f2bf(acc[1] * inv) << 16);
    p.y = (unsigned)f2bf(acc[2] * inv) | ((unsigned)f2bf(acc[3] * inv) << 16);
    p.z = (unsigned)f2bf(acc[4] * inv) | ((unsigned)f2bf(acc[5] * inv) << 16);
    p.w = (unsigned)f2bf(acc[6] * inv) | ((unsigned)f2bf(acc[7] * inv) << 16);
    *(uint4*)(outb + (size_t)g * 64 + q) = p;
}

// ---------------- MFMA GEMM 64x64 + sigmoid: t = sigmoid(agg@W+b) ----------
__global__ __launch_bounds__(256) void gemmsig_k(
    const unsigned short* __restrict__ Abf, const int* __restrict__ off,
    const unsigned short* __restrict__ img, const float* __restrict__ bias,
    unsigned short* __restrict__ out, int N)
{
    __shared__ alignas(16) unsigned short WT[64 * 72];
    __shared__ float bs[64];
    __shared__ unsigned char dz[64];

    const int tid = threadIdx.x;
    const int rowB = blockIdx.x * 64;
    {   // conflict-free uint4 staging from pre-built image
        const uint4* s = (const uint4*)(img + W1_OFF);
        uint4* d = (uint4*)WT;
        #pragma unroll
        for (int i = 0; i < 3; i++) {
            int idx = tid + i * 256;
            if (idx < 576) d[idx] = s[idx];
        }
    }
    if (tid < 64) {
        bs[tid] = bias[tid];
        int row = rowB + tid;
        dz[tid] = (row < N) ? (off[row + 1] == off[row]) : 0;
    }
    __syncthreads();

    const int w = tid >> 6, lane = tid & 63;
    const int m = lane & 15, quad = lane >> 4;
    const int row0 = rowB + w * 16;
    const int arow = min(row0 + m, N - 1);

    floatx4 acc[4];
    #pragma unroll
    for (int c = 0; c < 4; c++) acc[c] = (floatx4){0.f, 0.f, 0.f, 0.f};
    #pragma unroll
    for (int kk = 0; kk < 64; kk += 32) {
        short8 a = *(const short8*)(Abf + (size_t)arow * 64 + kk + quad * 8);
        #pragma unroll
        for (int c = 0; c < 4; c++) {
            short8 b = *(const short8*)(WT + (c * 16 + m) * 72 + kk + quad * 8);
            acc[c] = __builtin_amdgcn_mfma_f32_16x16x32_bf16(a, b, acc[c], 0, 0, 0);
        }
    }
    #pragma unroll
    for (int c = 0; c < 4; c++) {
        int col = c * 16 + m;
        #pragma unroll
        for (int r = 0; r < 4; r++) {
            int rl = w * 16 + quad * 4 + r;
            int row = rowB + rl;
            if (row < N) {
                float v = dz[rl] ? 0.5f : sigmoidf(acc[c][r] + bs[col]);
                out[(size_t)row * 64 + col] = f2bf(v);
            }
        }
    }
}

// ---------------- fused triple-GEMM epilogue (image-staged weights) --------
// t2 = sigmoid(agg@W2+b2); h3 = relu(t2@W3+b3); out = h3@W4+b4.
// T2/H3 tiles live only in LDS. ~66 KB LDS -> 2 blocks/CU (MFMA-dense, ok).
__global__ __launch_bounds__(256) void ep3b_k(
    const unsigned short* __restrict__ Abf, const int* __restrict__ off,
    const unsigned short* __restrict__ img,
    const float* __restrict__ b2, const float* __restrict__ b3,
    const float* __restrict__ b4, float* __restrict__ out, int N)
{
    __shared__ alignas(16) unsigned short W234[W234_SH];   // 39.8 KB
    __shared__ alignas(16) unsigned short T2[64 * 72];     // 9.0 KB
    __shared__ alignas(16) unsigned short H3[64 * 136];    // 17.0 KB
    __shared__ float b2s[64], b3s[128], b4s[48];
    __shared__ unsigned char dz[64];

    const unsigned short* W2T = W234;                       // 64 x 72
    const unsigned short* W3T = W234 + 64 * 72;             // 128 x 72
    const unsigned short* W4T = W234 + 64 * 72 + 128 * 72;  // 48 x 136

    const int tid = threadIdx.x;
    const int rowB = blockIdx.x * 64;
    {   // one contiguous conflict-free copy of all three weight images
        const uint4* s = (const uint4*)(img + W2_OFF);
        uint4* d = (uint4*)W234;
        for (int i = tid; i < W234_SH / 8; i += 256) d[i] = s[i];
    }
    if (tid < 64) {
        b2s[tid] = b2[tid];
        int row = rowB + tid;
        dz[tid] = (row < N) ? (off[row + 1] == off[row]) : 0;
    }
    if (tid < 128) b3s[tid] = b3[tid];
    if (tid < 48)  b4s[tid] = (tid < 40) ? b4[tid] : 0.f;
    __syncthreads();

    const int w = tid >> 6, lane = tid & 63;
    const int m = lane & 15, quad = lane >> 4;
    const int row0 = rowB + w * 16;

    // ---- phase 0: T2 = sigmoid(Agg @ W2 + b2) ----
    {
        floatx4 acc[4];
        #pragma unroll
        for (int c = 0; c < 4; c++) acc[c] = (floatx4){0.f, 0.f, 0.f, 0.f};
        const int arow = min(row0 + m, N - 1);
        #pragma unroll
        for (int kk = 0; kk < 64; kk += 32) {
            short8 a = *(const short8*)(Abf + (size_t)arow * 64 + kk + quad * 8);
            #pragma unroll
            for (int c = 0; c < 4; c++) {
                short8 b = *(const short8*)(W2T + (c * 16 + m) * 72 + kk + quad * 8);
                acc[c] = __builtin_amdgcn_mfma_f32_16x16x32_bf16(a, b, acc[c], 0, 0, 0);
            }
        }
        #pragma unroll
        for (int c = 0; c < 4; c++) {
            int col = c * 16 + m;
            #pragma unroll
            for (int r = 0; r < 4; r++) {
                int rl = w * 16 + quad * 4 + r;
                float v = dz[rl] ? 0.5f : sigmoidf(acc[c][r] + b2s[col]);
                T2[rl * 72 + col] = f2bf(v);
            }
        }
    }
    __syncthreads();

    // ---- phase 1: H3 = relu(T2 @ W3 + b3) ----
    {
        floatx4 acc[8];
        #pragma unroll
        for (int c = 0; c < 8; c++) acc[c] = (floatx4){0.f, 0.f, 0.f, 0.f};
        #pragma unroll
        for (int kk = 0; kk < 64; kk += 32) {
            short8 a = *(const short8*)(T2 + (w * 16 + m) * 72 + kk + quad * 8);
            #pragma unroll
            for (int c = 0; c < 8; c++) {
                short8 b = *(const short8*)(W3T + (c * 16 + m) * 72 + kk + quad * 8);
                acc[c] = __builtin_amdgcn_mfma_f32_16x16x32_bf16(a, b, acc[c], 0, 0, 0);
            }
        }
        #pragma unroll
        for (int c = 0; c < 8; c++) {
            int col = c * 16 + m;
            #pragma unroll
            for (int r = 0; r < 4; r++) {
                int rl = w * 16 + quad * 4 + r;
                H3[rl * 136 + col] = f2bf(fmaxf(acc[c][r] + b3s[col], 0.f));
            }
        }
    }
    __syncthreads();

    // ---- phase 2: out = H3 @ W4 + b4 ----
    {
        floatx4 acc[3];
        #pragma unroll
        for (int c = 0; c < 3; c++) acc[c] = (floatx4){0.f, 0.f, 0.f, 0.f};
        #pragma unroll
        for (int kk = 0; kk < 128; kk += 32) {
            short8 a = *(const short8*)(H3 + (w * 16 + m) * 136 + kk + quad * 8);
            #pragma unroll
            for (int c = 0; c < 3; c++) {
                short8 b = *(const short8*)(W4T + (c * 16 + m) * 136 + kk + quad * 8);
                acc[c] = __builtin_amdgcn_mfma_f32_16x16x32_bf16(a, b, acc[c], 0, 0, 0);
            }
        }
        #pragma unroll
        for (int c = 0; c < 3; c++) {
            int col = c * 16 + m;
            if (col < 40) {
                #pragma unroll
                for (int r = 0; r < 4; r++) {
                    int row = row0 + quad * 4 + r;
                    if (row < N) out[(size_t)row * 40 + col] = acc[c][r] + b4s[col];
                }
            }
        }
    }
}

extern "C" void kernel_launch(void* const* d_in, const int* in_sizes, int n_in,
                              void* d_out, int out_size, void* d_ws, size_t ws_size,
                              hipStream_t stream)
{
    const float* feat = (const float*)d_in[0];
    const int*   eidx = (const int*)d_in[1];
    const float* W1 = (const float*)d_in[2];
    const float* b1 = (const float*)d_in[3];
    const float* W2 = (const float*)d_in[4];
    const float* b2 = (const float*)d_in[5];
    const float* W3 = (const float*)d_in[6];
    const float* b3 = (const float*)d_in[7];
    const float* W4 = (const float*)d_in[8];
    const float* b4 = (const float*)d_in[9];

    const int N = in_sizes[0] / 64;
    const int E = in_sizes[1] / 2;
    const int* src = eidx;
    const int* dst = eidx + E;

    const int NBUCK = (N + CNODES - 1) / CNODES;   // 196

    unsigned short* featbf = (unsigned short*)d_ws;            // N*64 bf16
    unsigned short* t1     = featbf + (size_t)N * 64;          // N*64 bf16
    unsigned short* aggF   = t1     + (size_t)N * 64;          // N*64 bf16
    unsigned short* img    = aggF   + (size_t)N * 64;          // WIMG_TOT
    int*   off   = (int*)(img + ((WIMG_TOT + 7) & ~7));        // N+1
    int*   ccur  = off + (N + 1);                              // NBUCK
    int*   coff  = ccur + NBUCK;                               // NBUCK+1
    int*   ssrc  = coff + (NBUCK + 1);                         // E
    int*   arena = ssrc + E;                                   // NBUCK*CAP
    float* out   = (float*)d_out;

    hipMemsetAsync(ccur, 0, (size_t)NBUCK * sizeof(int), stream);

    const dim3 blk(256);
    const int gP  = (E + EPB - 1) / EPB;
    const int g64 = (N + 63) / 64;
    const int gC  = (N * 64 / 8 + 255) / 256;
    const int gW  = (WIMG_TOT + 255) / 256;
    const int gAg = (int)(((size_t)N * 8 + 255) / 256);

    // one-time prep + CSR build (shared by both aggregation rounds)
    cast_k<<<gC, blk, 0, stream>>>(feat, featbf, N * 64 / 8);
    prep_k<<<gW, blk, 0, stream>>>(W1, W2, W3, W4, img);
    part_a<<<gP, blk, 0, stream>>>(src, dst, ccur, arena, E, NBUCK);
    scanc_k<<<1, blk, 0, stream>>>(ccur, coff, off + N, NBUCK, E);
    csr_fine<<<NBUCK, blk, 0, stream>>>(arena, coff, off, ssrc, N);

    // aggF = mean(featbf[src]); t1 = sigmoid(aggF@W1+b1)
    agg_k<<<gAg, blk, 0, stream>>>(featbf, off, ssrc, aggF, N);
    gemmsig_k<<<g64, blk, 0, stream>>>(aggF, off, img, b1, t1, N);
    // aggF = mean(t1[src]); out = relu(sigmoid(aggF@W2+b2)@W3+b3)@W4+b4
    agg_k<<<gAg, blk, 0, stream>>>(t1, off, ssrc, aggF, N);
    ep3b_k<<<g64, blk, 0, stream>>>(aggF, off, img, b2, b3, b4, out, N);
}

// Round 11
// 235.855 us; speedup vs baseline: 1.1431x; 1.0435x over previous
//
#include <hip/hip_runtime.h>

// HGCN on MI355X. logmap0(expmap0(v)) == v here, so the model reduces to:
//   t1 = sigmoid(segmean(feat@W1+b1)); t2 = sigmoid(segmean(t1@W2+b2))
//   out = relu(t2@W3+b3)@W4 + b4     (segmean commutes with the linear map;
//   deg-0 nodes: segmean = 0 -> value 0.5 exactly, handled via dz flag)
// R1: fp32 atomicAdd scatter = atomic wall -> counting-sort CSR + gather.
// R2: single-block scan = latency wall -> hierarchical scan.
// R3: 4B random scatter write-allocates 64B lines -> coarse buckets.
// R4: global atomics on few counters = contention wall -> LDS-staged radix.
// R5: agg gather byte-bound -> bf16 rows, pack CSR.
// R6: fp32 MLP LDS-bound -> MFMA epilogue.
// R8: aggregate before GEMM (linearity); bf16 MFMA everywhere.
// R9/R10: pre-built weight images; latency-bound gather must stay
//   high-occupancy (unfused).
// R11: weights pre-packed in MFMA B-FRAGMENT order -> GEMMs read B operands
//   straight from global (coalesced, L1-hot); gemmsig becomes LDS-free;
//   ep3b LDS 66->27KB (occupancy up, 62MB staging traffic gone). scanc
//   folded into csr_fine; cast+prep merged; agg unrolled x8.

constexpr int CSHIFT = 9;               // 512 nodes per coarse bucket
constexpr int CNODES = 1 << CSHIFT;
constexpr int EPB    = 4096;            // edges per partition block
constexpr int EPT    = EPB / 256;
constexpr int CAP    = 16384;           // arena capacity per bucket (mean 8163)

// frag-packed bf16 weight image (shorts). Fragment = 16 lanes x 8 shorts =
// 128 shorts; flat idx = (((c*KK + kk)*4 + quad)*16 + m)*8 + j.
constexpr int W1F_OFF = 0;              // 4x2x4 frags  = 4096 shorts
constexpr int W2F_OFF = 4096;           // 4096
constexpr int W3F_OFF = 8192;           // 8x2x4 frags  = 8192
constexpr int W4F_OFF = 16384;          // 3x4x4 frags  = 6144 (cols padded 48)
constexpr int WIMG_TOT = 22528;

typedef __attribute__((ext_vector_type(8))) short short8;   // 8 bf16
typedef __attribute__((ext_vector_type(4))) float floatx4;  // MFMA acc

__device__ __forceinline__ float sigmoidf(float x) {
    return 1.0f / (1.0f + __expf(-x));
}
__device__ __forceinline__ unsigned short f2bf(float f) {   // RNE f32->bf16
    unsigned int u = __float_as_uint(f);
    u = (u + 0x7FFFu + ((u >> 16) & 1u)) >> 16;
    return (unsigned short)u;
}

// ---------------- one-time prep: feat cast + frag-packed weight image ------
__global__ __launch_bounds__(256) void prep_cast_k(
    const float* __restrict__ feat, unsigned short* __restrict__ featbf,
    const float* __restrict__ W1, const float* __restrict__ W2,
    const float* __restrict__ W3, const float* __restrict__ W4,
    unsigned short* __restrict__ img, int n8)
{
    int i = blockIdx.x * 256 + threadIdx.x;
    if (i < n8) {
        const float4* p = (const float4*)feat + (size_t)i * 2;
        float4 a = p[0], b = p[1];
        uint4 o;
        o.x = (unsigned)f2bf(a.x) | ((unsigned)f2bf(a.y) << 16);
        o.y = (unsigned)f2bf(a.z) | ((unsigned)f2bf(a.w) << 16);
        o.z = (unsigned)f2bf(b.x) | ((unsigned)f2bf(b.y) << 16);
        o.w = (unsigned)f2bf(b.z) | ((unsigned)f2bf(b.w) << 16);
        ((uint4*)featbf)[i] = o;
        return;
    }
    int t = i - n8;
    if (t >= WIMG_TOT) return;
    float v = 0.f;
    int s = t;
    if (s < W2F_OFF) {                       // W1 [64x64]
        int j = s & 7, m = (s >> 3) & 15, q = (s >> 7) & 3, kk = (s >> 9) & 1, c = s >> 10;
        v = W1[(kk * 32 + q * 8 + j) * 64 + c * 16 + m];
    } else if (s < W3F_OFF) {                // W2 [64x64]
        s -= W2F_OFF;
        int j = s & 7, m = (s >> 3) & 15, q = (s >> 7) & 3, kk = (s >> 9) & 1, c = s >> 10;
        v = W2[(kk * 32 + q * 8 + j) * 64 + c * 16 + m];
    } else if (s < W4F_OFF) {                // W3 [64x128]
        s -= W3F_OFF;
        int j = s & 7, m = (s >> 3) & 15, q = (s >> 7) & 3, kk = (s >> 9) & 1, c = s >> 10;
        v = W3[(kk * 32 + q * 8 + j) * 128 + c * 16 + m];
    } else {                                 // W4 [128x40], cols padded to 48
        s -= W4F_OFF;
        int j = s & 7, m = (s >> 3) & 15, q = (s >> 7) & 3, kk = (s >> 9) & 3, c = s >> 11;
        int n = c * 16 + m;
        if (n < 40) v = W4[(kk * 32 + q * 8 + j) * 40 + n];
    }
    img[t] = f2bf(v);
}

// ---------------- CSR build ----------------
__global__ __launch_bounds__(256) void part_a(const int* __restrict__ src,
                                              const int* __restrict__ dst,
                                              int* __restrict__ ccur,
                                              int* __restrict__ arena,
                                              int E, int NBUCK) {
    __shared__ int  hist[256];
    __shared__ int  exoff[256];
    __shared__ int  lcur[256];
    __shared__ int  gbase[256];
    __shared__ int  stage[EPB];
    __shared__ unsigned char stageB[EPB];

    const int tid = threadIdx.x;
    const int e0  = blockIdx.x * EPB;
    const int ec  = min(EPB, E - e0);

    int pk[EPT], bk[EPT];
    hist[tid] = 0;
    __syncthreads();
    #pragma unroll
    for (int j = 0; j < EPT; j++) {
        int idx = tid + j * 256;
        if (idx < ec) {
            int s = src[e0 + idx];
            int d = dst[e0 + idx];
            bk[j] = d >> CSHIFT;
            pk[j] = s | ((d & (CNODES - 1)) << 17);
            atomicAdd(&hist[bk[j]], 1);
        } else bk[j] = -1;
    }
    __syncthreads();
    const int h = hist[tid];
    exoff[tid] = h;
    __syncthreads();
    for (int dd = 1; dd < 256; dd <<= 1) {
        int v = 0;
        if (tid >= dd) v = exoff[tid - dd];
        __syncthreads();
        if (tid >= dd) exoff[tid] += v;
        __syncthreads();
    }
    const int ex = exoff[tid] - h;
    int gb = 0;
    if (tid < NBUCK && h > 0) gb = atomicAdd(ccur + tid, h);
    __syncthreads();
    exoff[tid] = ex;
    lcur[tid]  = ex;
    gbase[tid] = gb;
    __syncthreads();
    #pragma unroll
    for (int j = 0; j < EPT; j++) {
        if (bk[j] >= 0) {
            int l = atomicAdd(&lcur[bk[j]], 1);
            stage[l]  = pk[j];
            stageB[l] = (unsigned char)bk[j];
        }
    }
    __syncthreads();
    for (int i = tid; i < ec; i += 256) {
        int b = stageB[i];
        arena[(size_t)b * CAP + gbase[b] + (i - exoff[b])] = stage[i];
    }
}

// One block per coarse bucket: inline scan of bucket counts -> cbeg; then
// LDS counting sort over 512 nodes -> off/ssrc.
__global__ __launch_bounds__(256) void csr_fine(const int* __restrict__ arena,
                                                const int* __restrict__ ccur,
                                                int* __restrict__ off,
                                                int* __restrict__ ssrc,
                                                int N, int E, int NBUCK) {
    __shared__ int cnt[CNODES];
    __shared__ int cur[CNODES];
    __shared__ int part[256];
    const int b = blockIdx.x;
    const int node0 = b << CSHIFT;
    const int tid = threadIdx.x;

    // scan ccur[0..NBUCK) for this bucket's compact base
    part[tid] = (tid < NBUCK) ? ccur[tid] : 0;
    __syncthreads();
    for (int d = 1; d < 256; d <<= 1) {
        int v = 0;
        if (tid >= d) v = part[tid - d];
        __syncthreads();
        if (tid >= d) part[tid] += v;
        __syncthreads();
    }
    const int cbeg = (b > 0) ? part[b - 1] : 0;
    const int ec   = ccur[b];
    if (b == 0 && tid == 0) off[N] = E;
    __syncthreads();

    const int* pe = arena + (size_t)b * CAP;
    cnt[tid] = 0;
    cnt[tid + 256] = 0;
    __syncthreads();
    for (int i = tid; i < ec; i += 256)
        atomicAdd(&cnt[(pe[i] >> 17) & (CNODES - 1)], 1);
    __syncthreads();
    const int c0 = cnt[2 * tid], c1 = cnt[2 * tid + 1];
    part[tid] = c0 + c1;
    __syncthreads();
    for (int d = 1; d < 256; d <<= 1) {
        int v = 0;
        if (tid >= d) v = part[tid - d];
        __syncthreads();
        if (tid >= d) part[tid] += v;
        __syncthreads();
    }
    const int ex = (tid > 0) ? part[tid - 1] : 0;
    cur[2 * tid]     = ex;
    cur[2 * tid + 1] = ex + c0;
    if (node0 + 2 * tid     < N) off[node0 + 2 * tid]     = cbeg + ex;
    if (node0 + 2 * tid + 1 < N) off[node0 + 2 * tid + 1] = cbeg + ex + c0;
    __syncthreads();
    for (int i = tid; i < ec; i += 256) {
        int p = pe[i];
        int pos = cbeg + atomicAdd(&cur[(p >> 17) & (CNODES - 1)], 1);
        ssrc[pos] = p & 0x1FFFF;
    }
}

// ---------------- aggregation: pure mean gather, bf16->bf16 ----------------
#define ACC8(v)                                    \
    acc[0] += __uint_as_float((v).x << 16);        \
    acc[1] += __uint_as_float((v).x & 0xFFFF0000u);\
    acc[2] += __uint_as_float((v).y << 16);        \
    acc[3] += __uint_as_float((v).y & 0xFFFF0000u);\
    acc[4] += __uint_as_float((v).z << 16);        \
    acc[5] += __uint_as_float((v).z & 0xFFFF0000u);\
    acc[6] += __uint_as_float((v).w << 16);        \
    acc[7] += __uint_as_float((v).w & 0xFFFF0000u);

__global__ __launch_bounds__(256) void agg_k(const unsigned short* __restrict__ h,
                                             const int* __restrict__ off,
                                             const int* __restrict__ ssrc,
                                             unsigned short* __restrict__ outb,
                                             int N) {
    int t = blockIdx.x * 256 + threadIdx.x;
    int g = t >> 3;
    if (g >= N) return;
    int q = (t & 7) * 8;
    int beg = off[g], end = off[g + 1];
    float acc[8] = {0.f, 0.f, 0.f, 0.f, 0.f, 0.f, 0.f, 0.f};
    int i = beg;
    for (; i + 8 <= end; i += 8) {           // 8 loads in flight per lane
        uint4 v0 = *(const uint4*)(h + (size_t)ssrc[i]     * 64 + q);
        uint4 v1 = *(const uint4*)(h + (size_t)ssrc[i + 1] * 64 + q);
        uint4 v2 = *(const uint4*)(h + (size_t)ssrc[i + 2] * 64 + q);
        uint4 v3 = *(const uint4*)(h + (size_t)ssrc[i + 3] * 64 + q);
        uint4 v4 = *(const uint4*)(h + (size_t)ssrc[i + 4] * 64 + q);
        uint4 v5 = *(const uint4*)(h + (size_t)ssrc[i + 5] * 64 + q);
        uint4 v6 = *(const uint4*)(h + (size_t)ssrc[i + 6] * 64 + q);
        uint4 v7 = *(const uint4*)(h + (size_t)ssrc[i + 7] * 64 + q);
        ACC8(v0); ACC8(v1); ACC8(v2); ACC8(v3);
        ACC8(v4); ACC8(v5); ACC8(v6); ACC8(v7);
    }
    for (; i + 2 <= end; i += 2) {
        uint4 v0 = *(const uint4*)(h + (size_t)ssrc[i]     * 64 + q);
        uint4 v1 = *(const uint4*)(h + (size_t)ssrc[i + 1] * 64 + q);
        ACC8(v0); ACC8(v1);
    }
    for (; i < end; i++) {
        uint4 v = *(const uint4*)(h + (size_t)ssrc[i] * 64 + q);
        ACC8(v);
    }
    float inv = 1.0f / (float)max(end - beg, 1);
    uint4 p;
    p.x = (unsigned)f2bf(acc[0] * inv) | ((unsigned)f2bf(acc[1] * inv) << 16);
    p.y = (unsigned)f2bf(acc[2] * inv) | ((unsigned)f2bf(acc[3] * inv) << 16);
    p.z = (unsigned)f2bf(acc[4] * inv) | ((unsigned)f2bf(acc[5] * inv) << 16);
    p.w = (unsigned)f2bf(acc[6] * inv) | ((unsigned)f2bf(acc[7] * inv) << 16);
    *(uint4*)(outb + (size_t)g * 64 + q) = p;
}

// ---------------- MFMA GEMM 64x64 + sigmoid (LDS-FREE) ----------------
// B fragments streamed from frag-packed global image (coalesced, L1-hot).
__global__ __launch_bounds__(256) void gemmsig_k(
    const unsigned short* __restrict__ Abf, const int* __restrict__ off,
    const unsigned short* __restrict__ img, const float* __restrict__ bias,
    unsigned short* __restrict__ out, int N)
{
    const int tid = threadIdx.x;
    const int rowB = blockIdx.x * 64;
    const int w = tid >> 6, lane = tid & 63;
    const int m = lane & 15, quad = lane >> 4;
    const int row0 = rowB + w * 16;
    const int arow = min(row0 + m, N - 1);
    const short8* Wf = (const short8*)(img + W1F_OFF);

    floatx4 acc[4];
    #pragma unroll
    for (int c = 0; c < 4; c++) acc[c] = (floatx4){0.f, 0.f, 0.f, 0.f};
    #pragma unroll
    for (int kk = 0; kk < 2; kk++) {
        short8 a = *(const short8*)(Abf + (size_t)arow * 64 + kk * 32 + quad * 8);
        #pragma unroll
        for (int c = 0; c < 4; c++) {
            short8 b = Wf[((c * 2 + kk) * 4 + quad) * 16 + m];
            acc[c] = __builtin_amdgcn_mfma_f32_16x16x32_bf16(a, b, acc[c], 0, 0, 0);
        }
    }
    // dz per output row (deg-0 -> exact 0.5)
    bool dzr[4];
    int rows[4];
    #pragma unroll
    for (int r = 0; r < 4; r++) {
        rows[r] = row0 + quad * 4 + r;
        dzr[r] = (rows[r] < N) ? (off[rows[r] + 1] == off[rows[r]]) : false;
    }
    #pragma unroll
    for (int c = 0; c < 4; c++) {
        int col = c * 16 + m;
        float bv = bias[col];
        #pragma unroll
        for (int r = 0; r < 4; r++) {
            if (rows[r] < N) {
                float v = dzr[r] ? 0.5f : sigmoidf(acc[c][r] + bv);
                out[(size_t)rows[r] * 64 + col] = f2bf(v);
            }
        }
    }
}

// ---------------- fused triple-GEMM epilogue (frag-packed weights) --------
// t2 = sigmoid(agg@W2+b2); h3 = relu(t2@W3+b3); out = h3@W4+b4.
// Only T2/H3 tiles in LDS (~27 KB) -> high occupancy; B frags from global.
__global__ __launch_bounds__(256) void ep3b_k(
    const unsigned short* __restrict__ Abf, const int* __restrict__ off,
    const unsigned short* __restrict__ img,
    const float* __restrict__ b2, const float* __restrict__ b3,
    const float* __restrict__ b4, float* __restrict__ out, int N)
{
    __shared__ alignas(16) unsigned short T2[64 * 72];     // 9.0 KB
    __shared__ alignas(16) unsigned short H3[64 * 136];    // 17.0 KB

    const int tid = threadIdx.x;
    const int rowB = blockIdx.x * 64;
    const int w = tid >> 6, lane = tid & 63;
    const int m = lane & 15, quad = lane >> 4;
    const int row0 = rowB + w * 16;

    // ---- phase 0: T2 = sigmoid(Agg @ W2 + b2) ----
    {
        const short8* Wf = (const short8*)(img + W2F_OFF);
        floatx4 acc[4];
        #pragma unroll
        for (int c = 0; c < 4; c++) acc[c] = (floatx4){0.f, 0.f, 0.f, 0.f};
        const int arow = min(row0 + m, N - 1);
        #pragma unroll
        for (int kk = 0; kk < 2; kk++) {
            short8 a = *(const short8*)(Abf + (size_t)arow * 64 + kk * 32 + quad * 8);
            #pragma unroll
            for (int c = 0; c < 4; c++) {
                short8 b = Wf[((c * 2 + kk) * 4 + quad) * 16 + m];
                acc[c] = __builtin_amdgcn_mfma_f32_16x16x32_bf16(a, b, acc[c], 0, 0, 0);
            }
        }
        bool dzr[4];
        #pragma unroll
        for (int r = 0; r < 4; r++) {
            int row = row0 + quad * 4 + r;
            dzr[r] = (row < N) ? (off[row + 1] == off[row]) : false;
        }
        #pragma unroll
        for (int c = 0; c < 4; c++) {
            int col = c * 16 + m;
            float bv = b2[col];
            #pragma unroll
            for (int r = 0; r < 4; r++) {
                int rl = w * 16 + quad * 4 + r;
                float v = dzr[r] ? 0.5f : sigmoidf(acc[c][r] + bv);
                T2[rl * 72 + col] = f2bf(v);
            }
        }
    }
    __syncthreads();

    // ---- phase 1: H3 = relu(T2 @ W3 + b3) ----
    {
        const short8* Wf = (const short8*)(img + W3F_OFF);
        floatx4 acc[8];
        #pragma unroll
        for (int c = 0; c < 8; c++) acc[c] = (floatx4){0.f, 0.f, 0.f, 0.f};
        #pragma unroll
        for (int kk = 0; kk < 2; kk++) {
            short8 a = *(const short8*)(T2 + (w * 16 + m) * 72 + kk * 32 + quad * 8);
            #pragma unroll
            for (int c = 0; c < 8; c++) {
                short8 b = Wf[((c * 2 + kk) * 4 + quad) * 16 + m];
                acc[c] = __builtin_amdgcn_mfma_f32_16x16x32_bf16(a, b, acc[c], 0, 0, 0);
            }
        }
        #pragma unroll
        for (int c = 0; c < 8; c++) {
            int col = c * 16 + m;
            float bv = b3[col];
            #pragma unroll
            for (int r = 0; r < 4; r++) {
                int rl = w * 16 + quad * 4 + r;
                H3[rl * 136 + col] = f2bf(fmaxf(acc[c][r] + bv, 0.f));
            }
        }
    }
    __syncthreads();

    // ---- phase 2: out = H3 @ W4 + b4 ----
    {
        const short8* Wf = (const short8*)(img + W4F_OFF);
        floatx4 acc[3];
        #pragma unroll
        for (int c = 0; c < 3; c++) acc[c] = (floatx4){0.f, 0.f, 0.f, 0.f};
        #pragma unroll
        for (int kk = 0; kk < 4; kk++) {
            short8 a = *(const short8*)(H3 + (w * 16 + m) * 136 + kk * 32 + quad * 8);
            #pragma unroll
            for (int c = 0; c < 3; c++) {
                short8 b = Wf[((c * 4 + kk) * 4 + quad) * 16 + m];
                acc[c] = __builtin_amdgcn_mfma_f32_16x16x32_bf16(a, b, acc[c], 0, 0, 0);
            }
        }
        #pragma unroll
        for (int c = 0; c < 3; c++) {
            int col = c * 16 + m;
            if (col < 40) {
                float bv = b4[col];
                #pragma unroll
                for (int r = 0; r < 4; r++) {
                    int row = row0 + quad * 4 + r;
                    if (row < N) out[(size_t)row * 40 + col] = acc[c][r] + bv;
                }
            }
        }
    }
}

extern "C" void kernel_launch(void* const* d_in, const int* in_sizes, int n_in,
                              void* d_out, int out_size, void* d_ws, size_t ws_size,
                              hipStream_t stream)
{
    const float* feat = (const float*)d_in[0];
    const int*   eidx = (const int*)d_in[1];
    const float* W1 = (const float*)d_in[2];
    const float* b1 = (const float*)d_in[3];
    const float* W2 = (const float*)d_in[4];
    const float* b2 = (const float*)d_in[5];
    const float* W3 = (const float*)d_in[6];
    const float* b3 = (const float*)d_in[7];
    const float* W4 = (const float*)d_in[8];
    const float* b4 = (const float*)d_in[9];

    const int N = in_sizes[0] / 64;
    const int E = in_sizes[1] / 2;
    const int* src = eidx;
    const int* dst = eidx + E;

    const int NBUCK = (N + CNODES - 1) / CNODES;   // 196

    unsigned short* featbf = (unsigned short*)d_ws;            // N*64 bf16
    unsigned short* t1     = featbf + (size_t)N * 64;          // N*64 bf16
    unsigned short* aggF   = t1     + (size_t)N * 64;          // N*64 bf16
    unsigned short* img    = aggF   + (size_t)N * 64;          // WIMG_TOT
    int*   off   = (int*)(img + WIMG_TOT);                     // N+1
    int*   ccur  = off + (N + 1);                              // NBUCK
    int*   ssrc  = ccur + NBUCK;                               // E
    int*   arena = ssrc + E;                                   // NBUCK*CAP
    float* out   = (float*)d_out;

    hipMemsetAsync(ccur, 0, (size_t)NBUCK * sizeof(int), stream);

    const dim3 blk(256);
    const int gP  = (E + EPB - 1) / EPB;
    const int g64 = (N + 63) / 64;
    const int n8  = N * 64 / 8;
    const int gPC = (n8 + WIMG_TOT + 255) / 256;
    const int gAg = (int)(((size_t)N * 8 + 255) / 256);

    // one-time prep + CSR build (shared by both aggregation rounds)
    prep_cast_k<<<gPC, blk, 0, stream>>>(feat, featbf, W1, W2, W3, W4, img, n8);
    part_a<<<gP, blk, 0, stream>>>(src, dst, ccur, arena, E, NBUCK);
    csr_fine<<<NBUCK, blk, 0, stream>>>(arena, ccur, off, ssrc, N, E, NBUCK);

    // aggF = mean(featbf[src]); t1 = sigmoid(aggF@W1+b1)
    agg_k<<<gAg, blk, 0, stream>>>(featbf, off, ssrc, aggF, N);
    gemmsig_k<<<g64, blk, 0, stream>>>(aggF, off, img, b1, t1, N);
    // aggF = mean(t1[src]); out = relu(sigmoid(aggF@W2+b2)@W3+b3)@W4+b4
    agg_k<<<gAg, blk, 0, stream>>>(t1, off, ssrc, aggF, N);
    ep3b_k<<<g64, blk, 0, stream>>>(aggF, off, img, b2, b3, b4, out, N);
}

// Round 12
// 234.564 us; speedup vs baseline: 1.1493x; 1.0055x over previous
//
#include <hip/hip_runtime.h>

// HGCN on MI355X. logmap0(expmap0(v)) == v here, so the model reduces to:
//   t1 = sigmoid(segmean(feat@W1+b1)); t2 = sigmoid(segmean(t1@W2+b2))
//   out = relu(t2@W3+b3)@W4 + b4     (segmean commutes with the linear map;
//   deg-0 nodes: segmean = 0 -> value 0.5 exactly, handled via dz flag)
// R1: fp32 atomicAdd scatter = atomic wall -> counting-sort CSR + gather.
// R2: single-block scan = latency wall -> hierarchical scan.
// R3: 4B random scatter write-allocates 64B lines -> coarse buckets.
// R4: global atomics on few counters = contention wall -> LDS-staged radix.
// R5: agg gather byte-bound -> bf16 rows, pack CSR.
// R6: fp32 MLP LDS-bound -> MFMA epilogue.
// R8: aggregate before GEMM (linearity); bf16 MFMA everywhere.
// R9: fusing gather into 78KB-LDS kernel = 17% occupancy, LOST. R11:
//   frag-packed weight image -> GEMMs read B operands from global (L1-hot),
//   no weight LDS.
// R12: with weight LDS gone, re-fuse the gather: aggemm1 (9KB LDS) and
//   aggep3 (26.6KB via phase-aliased T2|Agg/H3 union, ~5 blocks/CU).
//   Deletes aggF buffer (2x25.6MB LLC roundtrip) + 2 launches.

constexpr int CSHIFT = 9;               // 512 nodes per coarse bucket
constexpr int CNODES = 1 << CSHIFT;
constexpr int EPB    = 4096;            // edges per partition block
constexpr int EPT    = EPB / 256;
constexpr int CAP    = 16384;           // arena capacity per bucket (mean 8163)

// frag-packed bf16 weight image (shorts). Fragment = 16 lanes x 8 shorts =
// 128 shorts; flat idx = (((c*KK + kk)*4 + quad)*16 + m)*8 + j.
constexpr int W1F_OFF = 0;              // 4x2x4 frags  = 4096 shorts
constexpr int W2F_OFF = 4096;           // 4096
constexpr int W3F_OFF = 8192;           // 8x2x4 frags  = 8192
constexpr int W4F_OFF = 16384;          // 3x4x4 frags  = 6144 (cols padded 48)
constexpr int WIMG_TOT = 22528;

typedef __attribute__((ext_vector_type(8))) short short8;   // 8 bf16
typedef __attribute__((ext_vector_type(4))) float floatx4;  // MFMA acc

__device__ __forceinline__ float sigmoidf(float x) {
    return 1.0f / (1.0f + __expf(-x));
}
__device__ __forceinline__ unsigned short f2bf(float f) {   // RNE f32->bf16
    unsigned int u = __float_as_uint(f);
    u = (u + 0x7FFFu + ((u >> 16) & 1u)) >> 16;
    return (unsigned short)u;
}

// ---------------- one-time prep: feat cast + frag-packed weight image ------
__global__ __launch_bounds__(256) void prep_cast_k(
    const float* __restrict__ feat, unsigned short* __restrict__ featbf,
    const float* __restrict__ W1, const float* __restrict__ W2,
    const float* __restrict__ W3, const float* __restrict__ W4,
    unsigned short* __restrict__ img, int n8)
{
    int i = blockIdx.x * 256 + threadIdx.x;
    if (i < n8) {
        const float4* p = (const float4*)feat + (size_t)i * 2;
        float4 a = p[0], b = p[1];
        uint4 o;
        o.x = (unsigned)f2bf(a.x) | ((unsigned)f2bf(a.y) << 16);
        o.y = (unsigned)f2bf(a.z) | ((unsigned)f2bf(a.w) << 16);
        o.z = (unsigned)f2bf(b.x) | ((unsigned)f2bf(b.y) << 16);
        o.w = (unsigned)f2bf(b.z) | ((unsigned)f2bf(b.w) << 16);
        ((uint4*)featbf)[i] = o;
        return;
    }
    int t = i - n8;
    if (t >= WIMG_TOT) return;
    float v = 0.f;
    int s = t;
    if (s < W2F_OFF) {                       // W1 [64x64]
        int j = s & 7, m = (s >> 3) & 15, q = (s >> 7) & 3, kk = (s >> 9) & 1, c = s >> 10;
        v = W1[(kk * 32 + q * 8 + j) * 64 + c * 16 + m];
    } else if (s < W3F_OFF) {                // W2 [64x64]
        s -= W2F_OFF;
        int j = s & 7, m = (s >> 3) & 15, q = (s >> 7) & 3, kk = (s >> 9) & 1, c = s >> 10;
        v = W2[(kk * 32 + q * 8 + j) * 64 + c * 16 + m];
    } else if (s < W4F_OFF) {                // W3 [64x128]
        s -= W3F_OFF;
        int j = s & 7, m = (s >> 3) & 15, q = (s >> 7) & 3, kk = (s >> 9) & 1, c = s >> 10;
        v = W3[(kk * 32 + q * 8 + j) * 128 + c * 16 + m];
    } else {                                 // W4 [128x40], cols padded to 48
        s -= W4F_OFF;
        int j = s & 7, m = (s >> 3) & 15, q = (s >> 7) & 3, kk = (s >> 9) & 3, c = s >> 11;
        int n = c * 16 + m;
        if (n < 40) v = W4[(kk * 32 + q * 8 + j) * 40 + n];
    }
    img[t] = f2bf(v);
}

// ---------------- CSR build ----------------
__global__ __launch_bounds__(256) void part_a(const int* __restrict__ src,
                                              const int* __restrict__ dst,
                                              int* __restrict__ ccur,
                                              int* __restrict__ arena,
                                              int E, int NBUCK) {
    __shared__ int  hist[256];
    __shared__ int  exoff[256];
    __shared__ int  lcur[256];
    __shared__ int  gbase[256];
    __shared__ int  stage[EPB];
    __shared__ unsigned char stageB[EPB];

    const int tid = threadIdx.x;
    const int e0  = blockIdx.x * EPB;
    const int ec  = min(EPB, E - e0);

    int pk[EPT], bk[EPT];
    hist[tid] = 0;
    __syncthreads();
    #pragma unroll
    for (int j = 0; j < EPT; j++) {
        int idx = tid + j * 256;
        if (idx < ec) {
            int s = src[e0 + idx];
            int d = dst[e0 + idx];
            bk[j] = d >> CSHIFT;
            pk[j] = s | ((d & (CNODES - 1)) << 17);
            atomicAdd(&hist[bk[j]], 1);
        } else bk[j] = -1;
    }
    __syncthreads();
    const int h = hist[tid];
    exoff[tid] = h;
    __syncthreads();
    for (int dd = 1; dd < 256; dd <<= 1) {
        int v = 0;
        if (tid >= dd) v = exoff[tid - dd];
        __syncthreads();
        if (tid >= dd) exoff[tid] += v;
        __syncthreads();
    }
    const int ex = exoff[tid] - h;
    int gb = 0;
    if (tid < NBUCK && h > 0) gb = atomicAdd(ccur + tid, h);
    __syncthreads();
    exoff[tid] = ex;
    lcur[tid]  = ex;
    gbase[tid] = gb;
    __syncthreads();
    #pragma unroll
    for (int j = 0; j < EPT; j++) {
        if (bk[j] >= 0) {
            int l = atomicAdd(&lcur[bk[j]], 1);
            stage[l]  = pk[j];
            stageB[l] = (unsigned char)bk[j];
        }
    }
    __syncthreads();
    for (int i = tid; i < ec; i += 256) {
        int b = stageB[i];
        arena[(size_t)b * CAP + gbase[b] + (i - exoff[b])] = stage[i];
    }
}

// One block per coarse bucket: inline scan of bucket counts -> cbeg; then
// LDS counting sort over 512 nodes -> off/ssrc.
__global__ __launch_bounds__(256) void csr_fine(const int* __restrict__ arena,
                                                const int* __restrict__ ccur,
                                                int* __restrict__ off,
                                                int* __restrict__ ssrc,
                                                int N, int E, int NBUCK) {
    __shared__ int cnt[CNODES];
    __shared__ int cur[CNODES];
    __shared__ int part[256];
    const int b = blockIdx.x;
    const int node0 = b << CSHIFT;
    const int tid = threadIdx.x;

    part[tid] = (tid < NBUCK) ? ccur[tid] : 0;
    __syncthreads();
    for (int d = 1; d < 256; d <<= 1) {
        int v = 0;
        if (tid >= d) v = part[tid - d];
        __syncthreads();
        if (tid >= d) part[tid] += v;
        __syncthreads();
    }
    const int cbeg = (b > 0) ? part[b - 1] : 0;
    const int ec   = ccur[b];
    if (b == 0 && tid == 0) off[N] = E;
    __syncthreads();

    const int* pe = arena + (size_t)b * CAP;
    cnt[tid] = 0;
    cnt[tid + 256] = 0;
    __syncthreads();
    for (int i = tid; i < ec; i += 256)
        atomicAdd(&cnt[(pe[i] >> 17) & (CNODES - 1)], 1);
    __syncthreads();
    const int c0 = cnt[2 * tid], c1 = cnt[2 * tid + 1];
    part[tid] = c0 + c1;
    __syncthreads();
    for (int d = 1; d < 256; d <<= 1) {
        int v = 0;
        if (tid >= d) v = part[tid - d];
        __syncthreads();
        if (tid >= d) part[tid] += v;
        __syncthreads();
    }
    const int ex = (tid > 0) ? part[tid - 1] : 0;
    cur[2 * tid]     = ex;
    cur[2 * tid + 1] = ex + c0;
    if (node0 + 2 * tid     < N) off[node0 + 2 * tid]     = cbeg + ex;
    if (node0 + 2 * tid + 1 < N) off[node0 + 2 * tid + 1] = cbeg + ex + c0;
    __syncthreads();
    for (int i = tid; i < ec; i += 256) {
        int p = pe[i];
        int pos = cbeg + atomicAdd(&cur[(p >> 17) & (CNODES - 1)], 1);
        ssrc[pos] = p & 0x1FFFF;
    }
}

// ---------------- gather helper: mean of h[src] rows into LDS tile ----------
#define ACC8(v)                                    \
    acc[0] += __uint_as_float((v).x << 16);        \
    acc[1] += __uint_as_float((v).x & 0xFFFF0000u);\
    acc[2] += __uint_as_float((v).y << 16);        \
    acc[3] += __uint_as_float((v).y & 0xFFFF0000u);\
    acc[4] += __uint_as_float((v).z << 16);        \
    acc[5] += __uint_as_float((v).z & 0xFFFF0000u);\
    acc[6] += __uint_as_float((v).w << 16);        \
    acc[7] += __uint_as_float((v).w & 0xFFFF0000u);

// 256 threads = 32 nodes x 8 lanes; 2 passes cover 64 rows. Zero-fills tails.
__device__ __forceinline__ void gather_tile(
    const unsigned short* __restrict__ h, const int* __restrict__ off,
    const int* __restrict__ ssrc, unsigned short* Agg, int rowB, int N, int tid)
{
    #pragma unroll
    for (int pass = 0; pass < 2; pass++) {
        int rl = pass * 32 + (tid >> 3);
        int g  = rowB + rl;
        int q  = (tid & 7) * 8;
        uint4 p = make_uint4(0u, 0u, 0u, 0u);
        if (g < N) {
            int beg = off[g], end = off[g + 1];
            float acc[8] = {0.f, 0.f, 0.f, 0.f, 0.f, 0.f, 0.f, 0.f};
            int i = beg;
            for (; i + 8 <= end; i += 8) {       // 8 loads in flight per lane
                uint4 v0 = *(const uint4*)(h + (size_t)ssrc[i]     * 64 + q);
                uint4 v1 = *(const uint4*)(h + (size_t)ssrc[i + 1] * 64 + q);
                uint4 v2 = *(const uint4*)(h + (size_t)ssrc[i + 2] * 64 + q);
                uint4 v3 = *(const uint4*)(h + (size_t)ssrc[i + 3] * 64 + q);
                uint4 v4 = *(const uint4*)(h + (size_t)ssrc[i + 4] * 64 + q);
                uint4 v5 = *(const uint4*)(h + (size_t)ssrc[i + 5] * 64 + q);
                uint4 v6 = *(const uint4*)(h + (size_t)ssrc[i + 6] * 64 + q);
                uint4 v7 = *(const uint4*)(h + (size_t)ssrc[i + 7] * 64 + q);
                ACC8(v0); ACC8(v1); ACC8(v2); ACC8(v3);
                ACC8(v4); ACC8(v5); ACC8(v6); ACC8(v7);
            }
            for (; i + 2 <= end; i += 2) {
                uint4 v0 = *(const uint4*)(h + (size_t)ssrc[i]     * 64 + q);
                uint4 v1 = *(const uint4*)(h + (size_t)ssrc[i + 1] * 64 + q);
                ACC8(v0); ACC8(v1);
            }
            for (; i < end; i++) {
                uint4 v = *(const uint4*)(h + (size_t)ssrc[i] * 64 + q);
                ACC8(v);
            }
            float inv = 1.0f / (float)max(end - beg, 1);
            p.x = (unsigned)f2bf(acc[0]*inv) | ((unsigned)f2bf(acc[1]*inv) << 16);
            p.y = (unsigned)f2bf(acc[2]*inv) | ((unsigned)f2bf(acc[3]*inv) << 16);
            p.z = (unsigned)f2bf(acc[4]*inv) | ((unsigned)f2bf(acc[5]*inv) << 16);
            p.w = (unsigned)f2bf(acc[6]*inv) | ((unsigned)f2bf(acc[7]*inv) << 16);
        }
        *(uint4*)(Agg + rl * 72 + q) = p;
    }
}

// ---------------- fused gather + GEMM1 + sigmoid -> t1 (9KB LDS) ----------
__global__ __launch_bounds__(256) void aggemm1_k(
    const unsigned short* __restrict__ featbf, const int* __restrict__ off,
    const int* __restrict__ ssrc, const unsigned short* __restrict__ img,
    const float* __restrict__ bias, unsigned short* __restrict__ t1, int N)
{
    __shared__ alignas(16) unsigned short Agg[64 * 72];   // 9.2 KB

    const int tid = threadIdx.x;
    const int rowB = blockIdx.x * 64;
    gather_tile(featbf, off, ssrc, Agg, rowB, N, tid);
    __syncthreads();

    const int w = tid >> 6, lane = tid & 63;
    const int m = lane & 15, quad = lane >> 4;
    const int row0 = rowB + w * 16;
    const short8* Wf = (const short8*)(img + W1F_OFF);

    floatx4 acc[4];
    #pragma unroll
    for (int c = 0; c < 4; c++) acc[c] = (floatx4){0.f, 0.f, 0.f, 0.f};
    #pragma unroll
    for (int kk = 0; kk < 2; kk++) {
        short8 a = *(const short8*)(Agg + (w * 16 + m) * 72 + kk * 32 + quad * 8);
        #pragma unroll
        for (int c = 0; c < 4; c++) {
            short8 b = Wf[((c * 2 + kk) * 4 + quad) * 16 + m];
            acc[c] = __builtin_amdgcn_mfma_f32_16x16x32_bf16(a, b, acc[c], 0, 0, 0);
        }
    }
    bool dzr[4];
    int rows[4];
    #pragma unroll
    for (int r = 0; r < 4; r++) {
        rows[r] = row0 + quad * 4 + r;
        dzr[r] = (rows[r] < N) ? (off[rows[r] + 1] == off[rows[r]]) : false;
    }
    #pragma unroll
    for (int c = 0; c < 4; c++) {
        int col = c * 16 + m;
        float bv = bias[col];
        #pragma unroll
        for (int r = 0; r < 4; r++) {
            if (rows[r] < N) {
                float v = dzr[r] ? 0.5f : sigmoidf(acc[c][r] + bv);
                t1[(size_t)rows[r] * 64 + col] = f2bf(v);
            }
        }
    }
}

// ---------------- fused gather + triple-GEMM -> out (26.6KB LDS) ----------
// LDS union: T2[0,9K) | Agg[9K,18K) | H3[9K,26.6K) (Agg dead after phase0).
__global__ __launch_bounds__(256) void aggep3_k(
    const unsigned short* __restrict__ t1, const int* __restrict__ off,
    const int* __restrict__ ssrc, const unsigned short* __restrict__ img,
    const float* __restrict__ b2, const float* __restrict__ b3,
    const float* __restrict__ b4, float* __restrict__ out, int N)
{
    __shared__ alignas(16) unsigned short SM[13312];   // 26.6 KB
    unsigned short* T2  = SM;            // 4608 shorts
    unsigned short* Agg = SM + 4608;     // 4608 shorts
    unsigned short* H3  = SM + 4608;     // 8704 shorts (aliases Agg)

    const int tid = threadIdx.x;
    const int rowB = blockIdx.x * 64;
    gather_tile(t1, off, ssrc, Agg, rowB, N, tid);
    __syncthreads();

    const int w = tid >> 6, lane = tid & 63;
    const int m = lane & 15, quad = lane >> 4;
    const int row0 = rowB + w * 16;

    // ---- phase 0: T2 = sigmoid(Agg @ W2 + b2) ----
    {
        const short8* Wf = (const short8*)(img + W2F_OFF);
        floatx4 acc[4];
        #pragma unroll
        for (int c = 0; c < 4; c++) acc[c] = (floatx4){0.f, 0.f, 0.f, 0.f};
        #pragma unroll
        for (int kk = 0; kk < 2; kk++) {
            short8 a = *(const short8*)(Agg + (w * 16 + m) * 72 + kk * 32 + quad * 8);
            #pragma unroll
            for (int c = 0; c < 4; c++) {
                short8 b = Wf[((c * 2 + kk) * 4 + quad) * 16 + m];
                acc[c] = __builtin_amdgcn_mfma_f32_16x16x32_bf16(a, b, acc[c], 0, 0, 0);
            }
        }
        bool dzr[4];
        #pragma unroll
        for (int r = 0; r < 4; r++) {
            int row = row0 + quad * 4 + r;
            dzr[r] = (row < N) ? (off[row + 1] == off[row]) : false;
        }
        __syncthreads();   // all Agg reads done before T2 writes? (T2 disjoint; barrier guards Agg->H3 alias later)
        #pragma unroll
        for (int c = 0; c < 4; c++) {
            int col = c * 16 + m;
            float bv = b2[col];
            #pragma unroll
            for (int r = 0; r < 4; r++) {
                int rl = w * 16 + quad * 4 + r;
                float v = dzr[r] ? 0.5f : sigmoidf(acc[c][r] + bv);
                T2[rl * 72 + col] = f2bf(v);
            }
        }
    }
    __syncthreads();

    // ---- phase 1: H3 = relu(T2 @ W3 + b3)  (H3 overwrites dead Agg) ----
    {
        const short8* Wf = (const short8*)(img + W3F_OFF);
        floatx4 acc[8];
        #pragma unroll
        for (int c = 0; c < 8; c++) acc[c] = (floatx4){0.f, 0.f, 0.f, 0.f};
        #pragma unroll
        for (int kk = 0; kk < 2; kk++) {
            short8 a = *(const short8*)(T2 + (w * 16 + m) * 72 + kk * 32 + quad * 8);
            #pragma unroll
            for (int c = 0; c < 8; c++) {
                short8 b = Wf[((c * 2 + kk) * 4 + quad) * 16 + m];
                acc[c] = __builtin_amdgcn_mfma_f32_16x16x32_bf16(a, b, acc[c], 0, 0, 0);
            }
        }
        #pragma unroll
        for (int c = 0; c < 8; c++) {
            int col = c * 16 + m;
            float bv = b3[col];
            #pragma unroll
            for (int r = 0; r < 4; r++) {
                int rl = w * 16 + quad * 4 + r;
                H3[rl * 136 + col] = f2bf(fmaxf(acc[c][r] + bv, 0.f));
            }
        }
    }
    __syncthreads();

    // ---- phase 2: out = H3 @ W4 + b4 ----
    {
        const short8* Wf = (const short8*)(img + W4F_OFF);
        floatx4 acc[3];
        #pragma unroll
        for (int c = 0; c < 3; c++) acc[c] = (floatx4){0.f, 0.f, 0.f, 0.f};
        #pragma unroll
        for (int kk = 0; kk < 4; kk++) {
            short8 a = *(const short8*)(H3 + (w * 16 + m) * 136 + kk * 32 + quad * 8);
            #pragma unroll
            for (int c = 0; c < 3; c++) {
                short8 b = Wf[((c * 4 + kk) * 4 + quad) * 16 + m];
                acc[c] = __builtin_amdgcn_mfma_f32_16x16x32_bf16(a, b, acc[c], 0, 0, 0);
            }
        }
        #pragma unroll
        for (int c = 0; c < 3; c++) {
            int col = c * 16 + m;
            if (col < 40) {
                float bv = b4[col];
                #pragma unroll
                for (int r = 0; r < 4; r++) {
                    int row = row0 + quad * 4 + r;
                    if (row < N) out[(size_t)row * 40 + col] = acc[c][r] + bv;
                }
            }
        }
    }
}

extern "C" void kernel_launch(void* const* d_in, const int* in_sizes, int n_in,
                              void* d_out, int out_size, void* d_ws, size_t ws_size,
                              hipStream_t stream)
{
    const float* feat = (const float*)d_in[0];
    const int*   eidx = (const int*)d_in[1];
    const float* W1 = (const float*)d_in[2];
    const float* b1 = (const float*)d_in[3];
    const float* W2 = (const float*)d_in[4];
    const float* b2 = (const float*)d_in[5];
    const float* W3 = (const float*)d_in[6];
    const float* b3 = (const float*)d_in[7];
    const float* W4 = (const float*)d_in[8];
    const float* b4 = (const float*)d_in[9];

    const int N = in_sizes[0] / 64;
    const int E = in_sizes[1] / 2;
    const int* src = eidx;
    const int* dst = eidx + E;

    const int NBUCK = (N + CNODES - 1) / CNODES;   // 196

    unsigned short* featbf = (unsigned short*)d_ws;            // N*64 bf16
    unsigned short* t1     = featbf + (size_t)N * 64;          // N*64 bf16
    unsigned short* img    = t1     + (size_t)N * 64;          // WIMG_TOT
    int*   off   = (int*)(img + WIMG_TOT);                     // N+1
    int*   ccur  = off + (N + 1);                              // NBUCK
    int*   ssrc  = ccur + NBUCK;                               // E
    int*   arena = ssrc + E;                                   // NBUCK*CAP
    float* out   = (float*)d_out;

    hipMemsetAsync(ccur, 0, (size_t)NBUCK * sizeof(int), stream);

    const dim3 blk(256);
    const int gP  = (E + EPB - 1) / EPB;
    const int g64 = (N + 63) / 64;
    const int n8  = N * 64 / 8;
    const int gPC = (n8 + WIMG_TOT + 255) / 256;

    // one-time prep + CSR build (shared by both aggregation rounds)
    prep_cast_k<<<gPC, blk, 0, stream>>>(feat, featbf, W1, W2, W3, W4, img, n8);
    part_a<<<gP, blk, 0, stream>>>(src, dst, ccur, arena, E, NBUCK);
    csr_fine<<<NBUCK, blk, 0, stream>>>(arena, ccur, off, ssrc, N, E, NBUCK);

    // t1 = sigmoid(mean(featbf[src]) @ W1 + b1)   [gather fused, 9KB LDS]
    aggemm1_k<<<g64, blk, 0, stream>>>(featbf, off, ssrc, img, b1, t1, N);
    // out = relu(sigmoid(mean(t1[src])@W2+b2)@W3+b3)@W4 + b4  [fused, 26.6KB]
    aggep3_k<<<g64, blk, 0, stream>>>(t1, off, ssrc, img, b2, b3, b4, out, N);
}

// Round 13
// 226.881 us; speedup vs baseline: 1.1883x; 1.0339x over previous
//
#include <hip/hip_runtime.h>

// HGCN on MI355X. logmap0(expmap0(v)) == v here, so the model reduces to:
//   t1 = sigmoid(segmean(feat@W1+b1)); t2 = sigmoid(segmean(t1@W2+b2))
//   out = relu(t2@W3+b3)@W4 + b4     (segmean commutes with the linear map;
//   deg-0 nodes: segmean = 0 -> value 0.5 exactly, handled via dz check)
// R1: fp32 atomicAdd scatter = atomic wall -> counting-sort CSR + gather.
// R2: single-block scan = latency wall -> hierarchical scan.
// R3: 4B random scatter write-allocates 64B lines -> coarse buckets.
// R4: global atomics on few counters = contention wall -> LDS-staged radix.
// R5: agg gather byte-bound -> bf16 rows, pack CSR.
// R6: fp32 MLP LDS-bound -> MFMA epilogue.
// R8: aggregate before GEMM (linearity); bf16 MFMA everywhere.
// R11: frag-packed weight image -> B operands from global (L1-hot), no
//   weight LDS. R12: re-fused gather, but 26.6KB LDS -> 6 blocks/CU, 32% occ.
// R13: whole pipeline made WAVE-LOCAL (wave w owns rows w*16..+15, incl.
//   gather) -> ZERO barriers; split-K phase2 halves H3 -> 18.4KB LDS ->
//   8 blocks/CU. prep merged into part_a launch.

constexpr int CSHIFT = 9;               // 512 nodes per coarse bucket
constexpr int CNODES = 1 << CSHIFT;
constexpr int EPB    = 4096;            // edges per partition block
constexpr int EPT    = EPB / 256;
constexpr int CAP    = 16384;           // arena capacity per bucket (mean 8163)

// frag-packed bf16 weight image (shorts). Fragment = 16 lanes x 8 shorts =
// 128 shorts; flat idx = (((c*KK + kk)*4 + quad)*16 + m)*8 + j.
constexpr int W1F_OFF = 0;              // 4x2x4 frags  = 4096 shorts
constexpr int W2F_OFF = 4096;           // 4096
constexpr int W3F_OFF = 8192;           // 8x2x4 frags  = 8192
constexpr int W4F_OFF = 16384;          // 3x4x4 frags  = 6144 (cols padded 48)
constexpr int WIMG_TOT = 22528;

typedef __attribute__((ext_vector_type(8))) short short8;   // 8 bf16
typedef __attribute__((ext_vector_type(4))) float floatx4;  // MFMA acc

__device__ __forceinline__ float sigmoidf(float x) {
    return 1.0f / (1.0f + __expf(-x));
}
__device__ __forceinline__ unsigned short f2bf(float f) {   // RNE f32->bf16
    unsigned int u = __float_as_uint(f);
    u = (u + 0x7FFFu + ((u >> 16) & 1u)) >> 16;
    return (unsigned short)u;
}

// ---------------- CSR partition + one-time prep (merged launch) ------------
// Blocks [0,gP): radix-partition edges into per-bucket arena regions.
// Blocks [gP,..): feat fp32->bf16 cast + frag-packed weight image build.
__global__ __launch_bounds__(256) void part_prep_k(
    const int* __restrict__ src, const int* __restrict__ dst,
    int* __restrict__ ccur, int* __restrict__ arena, int E, int NBUCK, int gP,
    const float* __restrict__ feat, unsigned short* __restrict__ featbf,
    const float* __restrict__ W1, const float* __restrict__ W2,
    const float* __restrict__ W3, const float* __restrict__ W4,
    unsigned short* __restrict__ img, int n8)
{
    __shared__ int  hist[256];
    __shared__ int  exoff[256];
    __shared__ int  lcur[256];
    __shared__ int  gbase[256];
    __shared__ int  stage[EPB];
    __shared__ unsigned char stageB[EPB];

    const int tid = threadIdx.x;

    if ((int)blockIdx.x >= gP) {
        // ---- prep path ----
        int i = ((int)blockIdx.x - gP) * 256 + tid;
        if (i < n8) {
            const float4* p = (const float4*)feat + (size_t)i * 2;
            float4 a = p[0], b = p[1];
            uint4 o;
            o.x = (unsigned)f2bf(a.x) | ((unsigned)f2bf(a.y) << 16);
            o.y = (unsigned)f2bf(a.z) | ((unsigned)f2bf(a.w) << 16);
            o.z = (unsigned)f2bf(b.x) | ((unsigned)f2bf(b.y) << 16);
            o.w = (unsigned)f2bf(b.z) | ((unsigned)f2bf(b.w) << 16);
            ((uint4*)featbf)[i] = o;
            return;
        }
        int t = i - n8;
        if (t >= WIMG_TOT) return;
        float v = 0.f;
        int s = t;
        if (s < W2F_OFF) {                       // W1 [64x64]
            int j = s & 7, m = (s >> 3) & 15, q = (s >> 7) & 3, kk = (s >> 9) & 1, c = s >> 10;
            v = W1[(kk * 32 + q * 8 + j) * 64 + c * 16 + m];
        } else if (s < W3F_OFF) {                // W2 [64x64]
            s -= W2F_OFF;
            int j = s & 7, m = (s >> 3) & 15, q = (s >> 7) & 3, kk = (s >> 9) & 1, c = s >> 10;
            v = W2[(kk * 32 + q * 8 + j) * 64 + c * 16 + m];
        } else if (s < W4F_OFF) {                // W3 [64x128]
            s -= W3F_OFF;
            int j = s & 7, m = (s >> 3) & 15, q = (s >> 7) & 3, kk = (s >> 9) & 1, c = s >> 10;
            v = W3[(kk * 32 + q * 8 + j) * 128 + c * 16 + m];
        } else {                                 // W4 [128x40], cols padded 48
            s -= W4F_OFF;
            int j = s & 7, m = (s >> 3) & 15, q = (s >> 7) & 3, kk = (s >> 9) & 3, c = s >> 11;
            int n = c * 16 + m;
            if (n < 40) v = W4[(kk * 32 + q * 8 + j) * 40 + n];
        }
        img[t] = f2bf(v);
        return;
    }

    // ---- partition path ----
    const int e0  = blockIdx.x * EPB;
    const int ec  = min(EPB, E - e0);

    int pk[EPT], bk[EPT];
    hist[tid] = 0;
    __syncthreads();
    #pragma unroll
    for (int j = 0; j < EPT; j++) {
        int idx = tid + j * 256;
        if (idx < ec) {
            int s = src[e0 + idx];
            int d = dst[e0 + idx];
            bk[j] = d >> CSHIFT;
            pk[j] = s | ((d & (CNODES - 1)) << 17);
            atomicAdd(&hist[bk[j]], 1);
        } else bk[j] = -1;
    }
    __syncthreads();
    const int h = hist[tid];
    exoff[tid] = h;
    __syncthreads();
    for (int dd = 1; dd < 256; dd <<= 1) {
        int v = 0;
        if (tid >= dd) v = exoff[tid - dd];
        __syncthreads();
        if (tid >= dd) exoff[tid] += v;
        __syncthreads();
    }
    const int ex = exoff[tid] - h;
    int gb = 0;
    if (tid < NBUCK && h > 0) gb = atomicAdd(ccur + tid, h);
    __syncthreads();
    exoff[tid] = ex;
    lcur[tid]  = ex;
    gbase[tid] = gb;
    __syncthreads();
    #pragma unroll
    for (int j = 0; j < EPT; j++) {
        if (bk[j] >= 0) {
            int l = atomicAdd(&lcur[bk[j]], 1);
            stage[l]  = pk[j];
            stageB[l] = (unsigned char)bk[j];
        }
    }
    __syncthreads();
    for (int i = tid; i < ec; i += 256) {
        int b = stageB[i];
        arena[(size_t)b * CAP + gbase[b] + (i - exoff[b])] = stage[i];
    }
}

// One block per coarse bucket: inline scan of bucket counts -> cbeg; then
// LDS counting sort over 512 nodes -> off/ssrc.
__global__ __launch_bounds__(256) void csr_fine(const int* __restrict__ arena,
                                                const int* __restrict__ ccur,
                                                int* __restrict__ off,
                                                int* __restrict__ ssrc,
                                                int N, int E, int NBUCK) {
    __shared__ int cnt[CNODES];
    __shared__ int cur[CNODES];
    __shared__ int part[256];
    const int b = blockIdx.x;
    const int node0 = b << CSHIFT;
    const int tid = threadIdx.x;

    part[tid] = (tid < NBUCK) ? ccur[tid] : 0;
    __syncthreads();
    for (int d = 1; d < 256; d <<= 1) {
        int v = 0;
        if (tid >= d) v = part[tid - d];
        __syncthreads();
        if (tid >= d) part[tid] += v;
        __syncthreads();
    }
    const int cbeg = (b > 0) ? part[b - 1] : 0;
    const int ec   = ccur[b];
    if (b == 0 && tid == 0) off[N] = E;
    __syncthreads();

    const int* pe = arena + (size_t)b * CAP;
    cnt[tid] = 0;
    cnt[tid + 256] = 0;
    __syncthreads();
    for (int i = tid; i < ec; i += 256)
        atomicAdd(&cnt[(pe[i] >> 17) & (CNODES - 1)], 1);
    __syncthreads();
    const int c0 = cnt[2 * tid], c1 = cnt[2 * tid + 1];
    part[tid] = c0 + c1;
    __syncthreads();
    for (int d = 1; d < 256; d <<= 1) {
        int v = 0;
        if (tid >= d) v = part[tid - d];
        __syncthreads();
        if (tid >= d) part[tid] += v;
        __syncthreads();
    }
    const int ex = (tid > 0) ? part[tid - 1] : 0;
    cur[2 * tid]     = ex;
    cur[2 * tid + 1] = ex + c0;
    if (node0 + 2 * tid     < N) off[node0 + 2 * tid]     = cbeg + ex;
    if (node0 + 2 * tid + 1 < N) off[node0 + 2 * tid + 1] = cbeg + ex + c0;
    __syncthreads();
    for (int i = tid; i < ec; i += 256) {
        int p = pe[i];
        int pos = cbeg + atomicAdd(&cur[(p >> 17) & (CNODES - 1)], 1);
        ssrc[pos] = p & 0x1FFFF;
    }
}

// ---------------- wave-local gather: mean of h[src] rows into LDS tile -----
// Wave w gathers ITS OWN rows w*16..w*16+15 (2 passes x 8 rows x 8 lanes).
// All later reads of Agg by wave w hit only these rows -> no barrier needed.
#define ACC8(v)                                    \
    acc[0] += __uint_as_float((v).x << 16);        \
    acc[1] += __uint_as_float((v).x & 0xFFFF0000u);\
    acc[2] += __uint_as_float((v).y << 16);        \
    acc[3] += __uint_as_float((v).y & 0xFFFF0000u);\
    acc[4] += __uint_as_float((v).z << 16);        \
    acc[5] += __uint_as_float((v).z & 0xFFFF0000u);\
    acc[6] += __uint_as_float((v).w << 16);        \
    acc[7] += __uint_as_float((v).w & 0xFFFF0000u);

__device__ __forceinline__ void gather_tile_wave(
    const unsigned short* __restrict__ h, const int* __restrict__ off,
    const int* __restrict__ ssrc, unsigned short* Agg, int rowB, int N,
    int w, int lane)
{
    #pragma unroll
    for (int pass = 0; pass < 2; pass++) {
        int rl = w * 16 + pass * 8 + (lane >> 3);
        int g  = rowB + rl;
        int q  = (lane & 7) * 8;
        uint4 p = make_uint4(0u, 0u, 0u, 0u);
        if (g < N) {
            int beg = off[g], end = off[g + 1];
            float acc[8] = {0.f, 0.f, 0.f, 0.f, 0.f, 0.f, 0.f, 0.f};
            int i = beg;
            for (; i + 8 <= end; i += 8) {       // 8 loads in flight per lane
                uint4 v0 = *(const uint4*)(h + (size_t)ssrc[i]     * 64 + q);
                uint4 v1 = *(const uint4*)(h + (size_t)ssrc[i + 1] * 64 + q);
                uint4 v2 = *(const uint4*)(h + (size_t)ssrc[i + 2] * 64 + q);
                uint4 v3 = *(const uint4*)(h + (size_t)ssrc[i + 3] * 64 + q);
                uint4 v4 = *(const uint4*)(h + (size_t)ssrc[i + 4] * 64 + q);
                uint4 v5 = *(const uint4*)(h + (size_t)ssrc[i + 5] * 64 + q);
                uint4 v6 = *(const uint4*)(h + (size_t)ssrc[i + 6] * 64 + q);
                uint4 v7 = *(const uint4*)(h + (size_t)ssrc[i + 7] * 64 + q);
                ACC8(v0); ACC8(v1); ACC8(v2); ACC8(v3);
                ACC8(v4); ACC8(v5); ACC8(v6); ACC8(v7);
            }
            for (; i + 2 <= end; i += 2) {
                uint4 v0 = *(const uint4*)(h + (size_t)ssrc[i]     * 64 + q);
                uint4 v1 = *(const uint4*)(h + (size_t)ssrc[i + 1] * 64 + q);
                ACC8(v0); ACC8(v1);
            }
            for (; i < end; i++) {
                uint4 v = *(const uint4*)(h + (size_t)ssrc[i] * 64 + q);
                ACC8(v);
            }
            float inv = 1.0f / (float)max(end - beg, 1);
            p.x = (unsigned)f2bf(acc[0]*inv) | ((unsigned)f2bf(acc[1]*inv) << 16);
            p.y = (unsigned)f2bf(acc[2]*inv) | ((unsigned)f2bf(acc[3]*inv) << 16);
            p.z = (unsigned)f2bf(acc[4]*inv) | ((unsigned)f2bf(acc[5]*inv) << 16);
            p.w = (unsigned)f2bf(acc[6]*inv) | ((unsigned)f2bf(acc[7]*inv) << 16);
        }
        *(uint4*)(Agg + rl * 72 + q) = p;
    }
}

// ---------------- fused gather + GEMM1 + sigmoid -> t1 (9KB LDS, 0 barriers)
__global__ __launch_bounds__(256) void aggemm1_k(
    const unsigned short* __restrict__ featbf, const int* __restrict__ off,
    const int* __restrict__ ssrc, const unsigned short* __restrict__ img,
    const float* __restrict__ bias, unsigned short* __restrict__ t1, int N)
{
    __shared__ alignas(16) unsigned short Agg[64 * 72];   // 9.2 KB

    const int tid = threadIdx.x;
    const int rowB = blockIdx.x * 64;
    const int w = tid >> 6, lane = tid & 63;
    const int m = lane & 15, quad = lane >> 4;
    const int row0 = rowB + w * 16;

    gather_tile_wave(featbf, off, ssrc, Agg, rowB, N, w, lane);

    const short8* Wf = (const short8*)(img + W1F_OFF);
    floatx4 acc[4];
    #pragma unroll
    for (int c = 0; c < 4; c++) acc[c] = (floatx4){0.f, 0.f, 0.f, 0.f};
    #pragma unroll
    for (int kk = 0; kk < 2; kk++) {
        short8 a = *(const short8*)(Agg + (w * 16 + m) * 72 + kk * 32 + quad * 8);
        #pragma unroll
        for (int c = 0; c < 4; c++) {
            short8 b = Wf[((c * 2 + kk) * 4 + quad) * 16 + m];
            acc[c] = __builtin_amdgcn_mfma_f32_16x16x32_bf16(a, b, acc[c], 0, 0, 0);
        }
    }
    bool dzr[4];
    int rows[4];
    #pragma unroll
    for (int r = 0; r < 4; r++) {
        rows[r] = row0 + quad * 4 + r;
        dzr[r] = (rows[r] < N) ? (off[rows[r] + 1] == off[rows[r]]) : false;
    }
    #pragma unroll
    for (int c = 0; c < 4; c++) {
        int col = c * 16 + m;
        float bv = bias[col];
        #pragma unroll
        for (int r = 0; r < 4; r++) {
            if (rows[r] < N) {
                float v = dzr[r] ? 0.5f : sigmoidf(acc[c][r] + bv);
                t1[(size_t)rows[r] * 64 + col] = f2bf(v);
            }
        }
    }
}

// ---------------- fused gather + triple-GEMM -> out (18.4KB LDS, 0 barriers)
// LDS: T2[0,4608) | Agg/H3half[4608,9216). Split-K phase2 over two H3 halves.
// Every LDS row is touched only by its owning wave -> in-wave ordering
// (lgkmcnt) is sufficient, no __syncthreads anywhere.
__global__ __launch_bounds__(256) void aggep3_k(
    const unsigned short* __restrict__ t1, const int* __restrict__ off,
    const int* __restrict__ ssrc, const unsigned short* __restrict__ img,
    const float* __restrict__ b2, const float* __restrict__ b3,
    const float* __restrict__ b4, float* __restrict__ out, int N)
{
    __shared__ alignas(16) unsigned short SM[9216];   // 18.4 KB
    unsigned short* T2  = SM;            // 64 x 72
    unsigned short* Agg = SM + 4608;     // 64 x 72 (dead after phase 0)
    unsigned short* H3h = SM + 4608;     // 64 x 72 (aliases Agg)

    const int tid = threadIdx.x;
    const int rowB = blockIdx.x * 64;
    const int w = tid >> 6, lane = tid & 63;
    const int m = lane & 15, quad = lane >> 4;
    const int row0 = rowB + w * 16;

    gather_tile_wave(t1, off, ssrc, Agg, rowB, N, w, lane);

    // ---- phase 0: T2 = sigmoid(Agg @ W2 + b2) ----
    {
        const short8* Wf = (const short8*)(img + W2F_OFF);
        floatx4 acc[4];
        #pragma unroll
        for (int c = 0; c < 4; c++) acc[c] = (floatx4){0.f, 0.f, 0.f, 0.f};
        #pragma unroll
        for (int kk = 0; kk < 2; kk++) {
            short8 a = *(const short8*)(Agg + (w * 16 + m) * 72 + kk * 32 + quad * 8);
            #pragma unroll
            for (int c = 0; c < 4; c++) {
                short8 b = Wf[((c * 2 + kk) * 4 + quad) * 16 + m];
                acc[c] = __builtin_amdgcn_mfma_f32_16x16x32_bf16(a, b, acc[c], 0, 0, 0);
            }
        }
        bool dzr[4];
        #pragma unroll
        for (int r = 0; r < 4; r++) {
            int row = row0 + quad * 4 + r;
            dzr[r] = (row < N) ? (off[row + 1] == off[row]) : false;
        }
        #pragma unroll
        for (int c = 0; c < 4; c++) {
            int col = c * 16 + m;
            float bv = b2[col];
            #pragma unroll
            for (int r = 0; r < 4; r++) {
                int rl = w * 16 + quad * 4 + r;
                float v = dzr[r] ? 0.5f : sigmoidf(acc[c][r] + bv);
                T2[rl * 72 + col] = f2bf(v);
            }
        }
    }

    // ---- phases 1&2 split-K: per half, H3h = relu(T2@W3half+b3half),
    //      then acc2 += H3h @ W4[khalf] ----
    floatx4 acc2[3];
    #pragma unroll
    for (int c = 0; c < 3; c++) acc2[c] = (floatx4){0.f, 0.f, 0.f, 0.f};
    const short8* Wf3 = (const short8*)(img + W3F_OFF);
    const short8* Wf4 = (const short8*)(img + W4F_OFF);

    #pragma unroll
    for (int half = 0; half < 2; half++) {
        floatx4 acc[4];
        #pragma unroll
        for (int c = 0; c < 4; c++) acc[c] = (floatx4){0.f, 0.f, 0.f, 0.f};
        #pragma unroll
        for (int kk = 0; kk < 2; kk++) {
            short8 a = *(const short8*)(T2 + (w * 16 + m) * 72 + kk * 32 + quad * 8);
            #pragma unroll
            for (int c = 0; c < 4; c++) {
                short8 b = Wf3[(((half * 4 + c) * 2 + kk) * 4 + quad) * 16 + m];
                acc[c] = __builtin_amdgcn_mfma_f32_16x16x32_bf16(a, b, acc[c], 0, 0, 0);
            }
        }
        #pragma unroll
        for (int c = 0; c < 4; c++) {
            int col = c * 16 + m;
            float bv = b3[half * 64 + col];
            #pragma unroll
            for (int r = 0; r < 4; r++) {
                int rl = w * 16 + quad * 4 + r;
                H3h[rl * 72 + col] = f2bf(fmaxf(acc[c][r] + bv, 0.f));
            }
        }
        #pragma unroll
        for (int kk2 = 0; kk2 < 2; kk2++) {
            short8 a = *(const short8*)(H3h + (w * 16 + m) * 72 + kk2 * 32 + quad * 8);
            #pragma unroll
            for (int c = 0; c < 3; c++) {
                short8 b = Wf4[((c * 4 + half * 2 + kk2) * 4 + quad) * 16 + m];
                acc2[c] = __builtin_amdgcn_mfma_f32_16x16x32_bf16(a, b, acc2[c], 0, 0, 0);
            }
        }
    }

    // ---- store out = acc2 + b4 ----
    #pragma unroll
    for (int c = 0; c < 3; c++) {
        int col = c * 16 + m;
        if (col < 40) {
            float bv = b4[col];
            #pragma unroll
            for (int r = 0; r < 4; r++) {
                int row = row0 + quad * 4 + r;
                if (row < N) out[(size_t)row * 40 + col] = acc2[c][r] + bv;
            }
        }
    }
}

extern "C" void kernel_launch(void* const* d_in, const int* in_sizes, int n_in,
                              void* d_out, int out_size, void* d_ws, size_t ws_size,
                              hipStream_t stream)
{
    const float* feat = (const float*)d_in[0];
    const int*   eidx = (const int*)d_in[1];
    const float* W1 = (const float*)d_in[2];
    const float* b1 = (const float*)d_in[3];
    const float* W2 = (const float*)d_in[4];
    const float* b2 = (const float*)d_in[5];
    const float* W3 = (const float*)d_in[6];
    const float* b3 = (const float*)d_in[7];
    const float* W4 = (const float*)d_in[8];
    const float* b4 = (const float*)d_in[9];

    const int N = in_sizes[0] / 64;
    const int E = in_sizes[1] / 2;
    const int* src = eidx;
    const int* dst = eidx + E;

    const int NBUCK = (N + CNODES - 1) / CNODES;   // 196

    unsigned short* featbf = (unsigned short*)d_ws;            // N*64 bf16
    unsigned short* t1     = featbf + (size_t)N * 64;          // N*64 bf16
    unsigned short* img    = t1     + (size_t)N * 64;          // WIMG_TOT
    int*   off   = (int*)(img + WIMG_TOT);                     // N+1
    int*   ccur  = off + (N + 1);                              // NBUCK
    int*   ssrc  = ccur + NBUCK;                               // E
    int*   arena = ssrc + E;                                   // NBUCK*CAP
    float* out   = (float*)d_out;

    hipMemsetAsync(ccur, 0, (size_t)NBUCK * sizeof(int), stream);

    const dim3 blk(256);
    const int gP  = (E + EPB - 1) / EPB;
    const int g64 = (N + 63) / 64;
    const int n8  = N * 64 / 8;
    const int gPC = (n8 + WIMG_TOT + 255) / 256;

    // CSR partition + prep (merged), then per-bucket counting sort
    part_prep_k<<<gP + gPC, blk, 0, stream>>>(src, dst, ccur, arena, E, NBUCK,
                                              gP, feat, featbf, W1, W2, W3, W4,
                                              img, n8);
    csr_fine<<<NBUCK, blk, 0, stream>>>(arena, ccur, off, ssrc, N, E, NBUCK);

    // t1 = sigmoid(mean(featbf[src]) @ W1 + b1)   [fused, 0 barriers]
    aggemm1_k<<<g64, blk, 0, stream>>>(featbf, off, ssrc, img, b1, t1, N);
    // out = relu(sigmoid(mean(t1[src])@W2+b2)@W3+b3)@W4 + b4  [fused, 0 barriers]
    aggep3_k<<<g64, blk, 0, stream>>>(t1, off, ssrc, img, b2, b3, b4, out, N);
}